// Round 12
// baseline (918.680 us; speedup 1.0000x reference)
//
#include <hip/hip_runtime.h>
#include <math.h>

#define HIDC 128
#define EDGEF 16
#define LAY 3
#define KNN 3
#define UU 4
#define NBLK 20000
#define NATOM (NBLK*UU)      // 80000
#define EBK 30000
#define EALL (EBK*UU*KNN)    // 360000
#define NGRP (EBK*UU)        // 120000 (edge,u) groups

#define W1F_L 36864          // 9 kb * 8 j * 64 lanes * 8
#define W2F_L 16384          // 4 kb * 8 j * 64 lanes * 8
#define NW1F_L 32768         // 8 kb * 8 j * 64 lanes * 8

#define E_WG 16              // block-edges per edge-kernel workgroup
#define ROWS_WG (E_WG*12)    // 192 rows
#define WAVES_WG 12

typedef __attribute__((ext_vector_type(8))) short bf16x8;
typedef __attribute__((ext_vector_type(4))) float f32x4;

__device__ __forceinline__ float silu_f(float v) {
    return __fdividef(v, 1.0f + __expf(-v));
}

__device__ __forceinline__ unsigned short f2bf(float f) {
    union { float f; unsigned int u; } v; v.f = f;
    unsigned int r = v.u + 0x7FFFu + ((v.u >> 16) & 1u);
    return (unsigned short)(r >> 16);
}

__device__ __forceinline__ float bf2f(unsigned short h) {
    union { unsigned int u; float f; } t; t.u = ((unsigned int)h) << 16;
    return t.f;
}

// full-precision split (RNE hi) — one-time weight prep only
__device__ __forceinline__ void split2(float v, short& hi, short& lo) {
    unsigned short h = f2bf(v);
    hi = (short)h;
    lo = (short)f2bf(v - bf2f(h));
}

// cheap split: truncated hi + RNE lo (lo captures truncation exactly; ~2^-17 rel)
__device__ __forceinline__ void csplit(float v, unsigned short& hi, unsigned short& lo) {
    unsigned int hu = __float_as_uint(v) & 0xffff0000u;
    hi = (unsigned short)(hu >> 16);
    lo = f2bf(v - __uint_as_float(hu));
}

// packed bf16 pair conversion: low16 = bf16(a), high16 = bf16(b)  [T12 recipe]
__device__ __forceinline__ unsigned int cvtpk2(float a, float b) {
    unsigned int r;
    asm("v_cvt_pk_bf16_f32 %0, %1, %2" : "=v"(r) : "v"(a), "v"(b));
    return r;
}

// async global->LDS DMA: 16B per lane, LDS dest = wave-uniform base + lane*16
__device__ __forceinline__ void stage16(const unsigned short* gsrc, unsigned short* ldst) {
    __builtin_amdgcn_global_load_lds(
        (const __attribute__((address_space(1))) unsigned int*)(const void*)gsrc,
        (__attribute__((address_space(3))) unsigned int*)(void*)ldst,
        16, 0, 0);
}

// ---------------- CSR build ----------------

__global__ void k_count(const int* __restrict__ edges, int* __restrict__ degB) {
    int e = blockIdx.x * 256 + threadIdx.x;
    if (e < EBK) atomicAdd(&degB[edges[e]], 1);
}

__global__ void k_scan(const int* __restrict__ degB, int* __restrict__ offB) {
    __shared__ int s[1024];
    __shared__ int carry;
    if (threadIdx.x == 0) carry = 0;
    __syncthreads();
    for (int base = 0; base < NBLK; base += 1024) {
        int i = base + threadIdx.x;
        int v = (i < NBLK) ? degB[i] : 0;
        s[threadIdx.x] = v;
        __syncthreads();
        for (int d = 1; d < 1024; d <<= 1) {
            int t = (threadIdx.x >= d) ? s[threadIdx.x - d] : 0;
            __syncthreads();
            s[threadIdx.x] += t;
            __syncthreads();
        }
        if (i < NBLK) offB[i] = carry + s[threadIdx.x] - v;
        int tot = s[1023];
        __syncthreads();
        if (threadIdx.x == 0) carry += tot;
        __syncthreads();
    }
    if (threadIdx.x == 0) offB[NBLK] = carry;
}

__global__ void k_fill(const int* __restrict__ edges, const int* __restrict__ offB,
                       int* __restrict__ cursor, int* __restrict__ listE) {
    int e = blockIdx.x * 256 + threadIdx.x;
    if (e < EBK) {
        int b = edges[e];
        int p = atomicAdd(&cursor[b], 1);
        listE[offB[b] + p] = e;
    }
}

// top-3 nearest dst atoms per src atom; exact f32, tie -> lower index (matches top_k)
__global__ void k_topk(const int* __restrict__ edges, const float* __restrict__ Z,
                       int* __restrict__ colIdx) {
    int t = blockIdx.x * 256 + threadIdx.x;
    if (t >= EBK * UU) return;
    int e = t >> 2, u = t & 3;
    int b0 = edges[e], b1 = edges[EBK + e];
    int s = b0 * UU + u;
    float zs0 = Z[s*3+0], zs1 = Z[s*3+1], zs2 = Z[s*3+2];
    float d2[UU];
    #pragma unroll
    for (int v = 0; v < UU; v++) {
        int d = b1 * UU + v;
        float a0 = __fsub_rn(zs0, Z[d*3+0]);
        float a1 = __fsub_rn(zs1, Z[d*3+1]);
        float a2 = __fsub_rn(zs2, Z[d*3+2]);
        float p0 = __fmul_rn(a0, a0);
        float p1 = __fmul_rn(a1, a1);
        float p2 = __fmul_rn(a2, a2);
        d2[v] = __fadd_rn(__fadd_rn(p0, p1), p2);
    }
    bool used[UU] = {false, false, false, false};
    #pragma unroll
    for (int k = 0; k < KNN; k++) {
        int best = -1;
        float bd = INFINITY;
        #pragma unroll
        for (int v = 0; v < UU; v++) {
            if (!used[v] && d2[v] < bd) { bd = d2[v]; best = v; }
        }
        used[best] = true;
        colIdx[t * KNN + k] = b1 * UU + best;
    }
}

// ---------------- weight fragment precompute (hi/lo bf16, MFMA B-layout) ----------------

__global__ void k_wfrag(const float* __restrict__ ew1, const float* __restrict__ ew2,
                        const float* __restrict__ cw1,
                        const float* __restrict__ nw1, const float* __restrict__ nw2,
                        unsigned short* __restrict__ w1f_hi, unsigned short* __restrict__ w1f_lo,
                        unsigned short* __restrict__ w2f_hi, unsigned short* __restrict__ w2f_lo,
                        unsigned short* __restrict__ c1f_hi, unsigned short* __restrict__ c1f_lo,
                        unsigned short* __restrict__ n1f_hi, unsigned short* __restrict__ n1f_lo,
                        unsigned short* __restrict__ n2f_hi, unsigned short* __restrict__ n2f_lo) {
    int i = blockIdx.x * 256 + threadIdx.x;
    float v = 0.f;
    unsigned short* dh = nullptr;
    unsigned short* dl = nullptr;
    int di = 0;
    if (i < 3 * W1F_L) {
        int l = i / W1F_L, rem = i % W1F_L;
        int chunk = rem >> 9, lane = (rem >> 3) & 63, t = rem & 7;
        int kb = chunk >> 3, j = chunk & 7;
        int k = kb*32 + (lane >> 4)*8 + t, n = j*16 + (lane & 15);
        v = (k < 273) ? ew1[(size_t)l*273*128 + (size_t)k*128 + n] : 0.f;
        dh = w1f_hi; dl = w1f_lo; di = i;
    } else {
        int i2 = i - 3 * W1F_L;
        if (i2 < 3 * W2F_L) {
            int l = i2 / W2F_L, rem = i2 % W2F_L;
            int chunk = rem >> 9, lane = (rem >> 3) & 63, t = rem & 7;
            int kb = chunk >> 3, j = chunk & 7;
            int k = kb*32 + (lane >> 4)*8 + t, n = j*16 + (lane & 15);
            v = ew2[(size_t)l*128*128 + (size_t)k*128 + n];
            dh = w2f_hi; dl = w2f_lo; di = i2;
        } else {
            int i3 = i2 - 3 * W2F_L;
            if (i3 < 3 * W2F_L) {
                int l = i3 / W2F_L, rem = i3 % W2F_L;
                int chunk = rem >> 9, lane = (rem >> 3) & 63, t = rem & 7;
                int kb = chunk >> 3, j = chunk & 7;
                int k = kb*32 + (lane >> 4)*8 + t, n = j*16 + (lane & 15);
                v = cw1[(size_t)l*128*128 + (size_t)k*128 + n];
                dh = c1f_hi; dl = c1f_lo; di = i3;
            } else {
                int i4 = i3 - 3 * W2F_L;
                if (i4 < 3 * NW1F_L) {
                    int l = i4 / NW1F_L, rem = i4 % NW1F_L;
                    int chunk = rem >> 9, lane = (rem >> 3) & 63, t = rem & 7;
                    int kb = chunk >> 3, j = chunk & 7;
                    int k = kb*32 + (lane >> 4)*8 + t, n = j*16 + (lane & 15);
                    v = nw1[(size_t)l*256*128 + (size_t)k*128 + n];
                    dh = n1f_hi; dl = n1f_lo; di = i4;
                } else {
                    int i5 = i4 - 3 * NW1F_L;
                    if (i5 >= 3 * W2F_L) return;
                    int l = i5 / W2F_L, rem = i5 % W2F_L;
                    int chunk = rem >> 9, lane = (rem >> 3) & 63, t = rem & 7;
                    int kb = chunk >> 3, j = chunk & 7;
                    int k = kb*32 + (lane >> 4)*8 + t, n = j*16 + (lane & 15);
                    v = nw2[(size_t)l*128*128 + (size_t)k*128 + n];
                    dh = n2f_hi; dl = n2f_lo; di = i5;
                }
            }
        }
    }
    short hi, lo;
    split2(v, hi, lo);
    dh[di] = (unsigned short)hi;
    dl[di] = (unsigned short)lo;
}

// ---------------- flat-12 fused edge pipeline (hybrid-precision MFMA) ----------------
// WG = 768 threads = 12 waves = 16 block-edges = 192 REAL rows (no kk padding).
// h stored as separate hi/lo bf16 planes -> A-fragments are direct 16B loads.

__global__ __launch_bounds__(768, 6) void k_edge_flat(
    const unsigned short* __restrict__ hHI,
    const unsigned short* __restrict__ hLO,
    const float* __restrict__ x,
    const float* __restrict__ eattr,
    const int* __restrict__ edges0,
    const int* __restrict__ colIdx,
    const unsigned short* __restrict__ w1f_hi, const unsigned short* __restrict__ w1f_lo,
    const unsigned short* __restrict__ w2f_hi, const unsigned short* __restrict__ w2f_lo,
    const unsigned short* __restrict__ c1f_hi, const unsigned short* __restrict__ c1f_lo,
    const float* __restrict__ eb1,
    const float* __restrict__ eb2,
    const float* __restrict__ cb1,
    const float* __restrict__ cw2v,
    unsigned short* __restrict__ msum,
    float* __restrict__ xsum)
{
    __shared__ unsigned short wbufH[4096], wbufL[4096];        // 16 KB
    __shared__ unsigned short Mlds[ROWS_WG * 128];             // 48 KB (C1, then M)
    __shared__ float diffLDS[ROWS_WG][3];                      // 2.25 KB
    __shared__ float pLDS[ROWS_WG];                            // 0.75 KB

    const int tid = threadIdx.x;
    const int wid = tid >> 6, l = tid & 63;
    const int g = l >> 4, er = l & 15;
    const int e_base = blockIdx.x * E_WG;
    const int r0 = wid * 16;

    // per-lane gather row (row = r0 + er)
    const int row_g = r0 + er;
    const int e_loc = row_g / 12;
    const int rr = row_g - e_loc * 12;
    const int u = rr / 3;
    const int kk = rr - u * 3;
    const int e = e_base + e_loc;
    const int bs = edges0[e];
    const int srcA = bs * 4 + u;
    const int colA = colIdx[(e * 4 + u) * 3 + kk];
    float rad = 0.f;
    if (g == 0) {
        float dx = x[srcA*3+0] - x[colA*3+0];
        float dy = x[srcA*3+1] - x[colA*3+1];
        float dz = x[srcA*3+2] - x[colA*3+2];
        rad = dx*dx + dy*dy + dz*dz;
        diffLDS[row_g][0] = dx; diffLDS[row_g][1] = dy; diffLDS[row_g][2] = dz;
    }

    // staging: waves 0..3 cover 16 KB/kb
    const int goff = wid * 512 + l * 8;               // shorts (valid for wid<4)
    unsigned short* lb0H = wbufH + wid * 512;
    unsigned short* lb1H = wbufH + 2048 + wid * 512;
    unsigned short* lb0L = wbufL + wid * 512;
    unsigned short* lb1L = wbufL + 2048 + wid * 512;

    // ---- phase 1: C1 = silu([h_r|h_c|rad|ea] @ W1 + b1), K=288, 3-MFMA split ----
    {
        f32x4 acc[8];
        #pragma unroll
        for (int jj = 0; jj < 8; jj++) acc[jj] = (f32x4){0.f, 0.f, 0.f, 0.f};

        #pragma unroll 1
        for (int kb = 0; kb < 9; kb++) {
            __syncthreads();
            if (wid < 4) {
                stage16(w1f_hi + (kb << 12) + goff,        lb0H);
                stage16(w1f_hi + (kb << 12) + 2048 + goff, lb1H);
                stage16(w1f_lo + (kb << 12) + goff,        lb0L);
                stage16(w1f_lo + (kb << 12) + 2048 + goff, lb1L);
            }
            bf16x8 ah, al;
            if (kb < 8) {
                const size_t off = (kb < 4) ? ((size_t)srcA * 128 + kb * 32 + g * 8)
                                            : ((size_t)colA * 128 + (kb - 4) * 32 + g * 8);
                ah = *(const bf16x8*)(hHI + off);
                al = *(const bf16x8*)(hLO + off);
            } else {
                float tv[8];
                #pragma unroll
                for (int q = 0; q < 8; q++) tv[q] = 0.f;
                if (g == 0) {
                    tv[0] = rad;
                    #pragma unroll
                    for (int q = 1; q < 8; q++) tv[q] = eattr[(size_t)e*16 + (q-1)];
                } else if (g == 1) {
                    #pragma unroll
                    for (int q = 0; q < 8; q++) tv[q] = eattr[(size_t)e*16 + 7 + q];
                } else if (g == 2) {
                    tv[0] = eattr[(size_t)e*16 + 15];
                }
                #pragma unroll
                for (int q = 0; q < 8; q++) { unsigned short hh, ll; csplit(tv[q], hh, ll); ah[q] = (short)hh; al[q] = (short)ll; }
            }
            __syncthreads();
            __builtin_amdgcn_s_setprio(1);
            #pragma unroll
            for (int jj = 0; jj < 8; jj++) {
                const int off = (jj << 9) + (l << 3);
                bf16x8 wh = *(const bf16x8*)&wbufH[off];
                bf16x8 wl = *(const bf16x8*)&wbufL[off];
                acc[jj] = __builtin_amdgcn_mfma_f32_16x16x32_bf16(ah, wh, acc[jj], 0, 0, 0);
                acc[jj] = __builtin_amdgcn_mfma_f32_16x16x32_bf16(al, wh, acc[jj], 0, 0, 0);
                acc[jj] = __builtin_amdgcn_mfma_f32_16x16x32_bf16(ah, wl, acc[jj], 0, 0, 0);
            }
            __builtin_amdgcn_s_setprio(0);
        }
        #pragma unroll
        for (int jp = 0; jp < 4; jp++) {
            const int n0 = (jp * 2) * 16 + er, n1 = n0 + 16;
            const float b0 = eb1[n0], b1 = eb1[n1];
            #pragma unroll
            for (int reg = 0; reg < 4; reg++) {
                const int row = r0 + g * 4 + reg;
                float v0 = silu_f(acc[jp*2][reg] + b0);
                float v1 = silu_f(acc[jp*2+1][reg] + b1);
                unsigned int pk = cvtpk2(v0, v1);
                const int m = (row & 7) << 3;
                Mlds[row * 128 + (n0 ^ m)] = (unsigned short)pk;
                Mlds[row * 128 + (n1 ^ m)] = (unsigned short)(pk >> 16);
            }
        }
    }

    // ---- phase 2: m = silu(C1 @ W2 + b2) -> Mlds (own rows) ----
    {
        f32x4 acc[8];
        #pragma unroll
        for (int jj = 0; jj < 8; jj++) acc[jj] = (f32x4){0.f, 0.f, 0.f, 0.f};

        #pragma unroll 1
        for (int kb = 0; kb < 4; kb++) {
            __syncthreads();
            if (wid < 4) {
                stage16(w2f_hi + (kb << 12) + goff,        lb0H);
                stage16(w2f_hi + (kb << 12) + 2048 + goff, lb1H);
                stage16(w2f_lo + (kb << 12) + goff,        lb0L);
                stage16(w2f_lo + (kb << 12) + 2048 + goff, lb1L);
            }
            const int aoff = row_g * 128 + ((kb * 32 + g * 8) ^ ((row_g & 7) << 3));
            bf16x8 a2 = *(const bf16x8*)&Mlds[aoff];
            __syncthreads();
            __builtin_amdgcn_s_setprio(1);
            #pragma unroll
            for (int jj = 0; jj < 8; jj++) {
                const int off = (jj << 9) + (l << 3);
                bf16x8 wh = *(const bf16x8*)&wbufH[off];
                bf16x8 wl = *(const bf16x8*)&wbufL[off];
                acc[jj] = __builtin_amdgcn_mfma_f32_16x16x32_bf16(a2, wh, acc[jj], 0, 0, 0);
                acc[jj] = __builtin_amdgcn_mfma_f32_16x16x32_bf16(a2, wl, acc[jj], 0, 0, 0);
            }
            __builtin_amdgcn_s_setprio(0);
        }
        #pragma unroll
        for (int jp = 0; jp < 4; jp++) {
            const int n0 = (jp * 2) * 16 + er, n1 = n0 + 16;
            const float b0 = eb2[n0], b1 = eb2[n1];
            #pragma unroll
            for (int reg = 0; reg < 4; reg++) {
                const int row = r0 + g * 4 + reg;
                float v0 = silu_f(acc[jp*2][reg] + b0);
                float v1 = silu_f(acc[jp*2+1][reg] + b1);
                unsigned int pk = cvtpk2(v0, v1);
                const int m = (row & 7) << 3;
                Mlds[row * 128 + (n0 ^ m)] = (unsigned short)pk;
                Mlds[row * 128 + (n1 ^ m)] = (unsigned short)(pk >> 16);
            }
        }
    }

    // ---- phase 3: w = silu(m @ CW1 + cb1) @ cw2; p per row -> pLDS ----
    {
        f32x4 acc[8];
        #pragma unroll
        for (int jj = 0; jj < 8; jj++) acc[jj] = (f32x4){0.f, 0.f, 0.f, 0.f};

        #pragma unroll 1
        for (int kb = 0; kb < 4; kb++) {
            __syncthreads();
            if (wid < 4) {
                stage16(c1f_hi + (kb << 12) + goff,        lb0H);
                stage16(c1f_hi + (kb << 12) + 2048 + goff, lb1H);
                stage16(c1f_lo + (kb << 12) + goff,        lb0L);
                stage16(c1f_lo + (kb << 12) + 2048 + goff, lb1L);
            }
            const int aoff = row_g * 128 + ((kb * 32 + g * 8) ^ ((row_g & 7) << 3));
            bf16x8 a3 = *(const bf16x8*)&Mlds[aoff];
            __syncthreads();
            __builtin_amdgcn_s_setprio(1);
            #pragma unroll
            for (int jj = 0; jj < 8; jj++) {
                const int off = (jj << 9) + (l << 3);
                bf16x8 wh = *(const bf16x8*)&wbufH[off];
                bf16x8 wl = *(const bf16x8*)&wbufL[off];
                acc[jj] = __builtin_amdgcn_mfma_f32_16x16x32_bf16(a3, wh, acc[jj], 0, 0, 0);
                acc[jj] = __builtin_amdgcn_mfma_f32_16x16x32_bf16(a3, wl, acc[jj], 0, 0, 0);
            }
            __builtin_amdgcn_s_setprio(0);
        }
        float p[4] = {0.f, 0.f, 0.f, 0.f};
        #pragma unroll
        for (int jj = 0; jj < 8; jj++) {
            const int n = jj * 16 + er;
            const float cb = cb1[n], cw = cw2v[n];
            #pragma unroll
            for (int reg = 0; reg < 4; reg++)
                p[reg] += silu_f(acc[jj][reg] + cb) * cw;
        }
        #pragma unroll
        for (int d = 1; d < 16; d <<= 1) {
            #pragma unroll
            for (int reg = 0; reg < 4; reg++)
                p[reg] += __shfl_xor(p[reg], d);
        }
        if (er == 0) {
            #pragma unroll
            for (int reg = 0; reg < 4; reg++)
                pLDS[r0 + g * 4 + reg] = p[reg];
        }
    }
    __syncthreads();

    // ---- merged tail: msum (u32 col-pairs) + xsum ----
    for (int t = tid; t < E_WG * 4 * 64; t += 768) {
        const int gi = t >> 6, cp = t & 63;
        const int c0 = cp * 2;
        const int el = gi >> 2, uu2 = gi & 3;
        const int base = el * 12 + uu2 * 3;
        float s0 = 0.f, s1 = 0.f;
        #pragma unroll
        for (int k3 = 0; k3 < 3; k3++) {
            const int row = base + k3;
            const int m = (row & 7) << 3;
            unsigned int pr = *(const unsigned int*)&Mlds[row * 128 + (c0 ^ m)];
            s0 += bf2f((unsigned short)(pr & 0xffffu));
            s1 += bf2f((unsigned short)(pr >> 16));
        }
        ((unsigned int*)msum)[(size_t)((e_base + el) * 4 + uu2) * 64 + cp] = cvtpk2(s0, s1);
    }
    if (tid < E_WG * 4 * 3) {
        const int gi = tid / 3, c = tid - gi * 3;
        const int el = gi >> 2, uu2 = gi & 3;
        const int base = el * 12 + uu2 * 3;
        float xs = 0.f;
        #pragma unroll
        for (int k3 = 0; k3 < 3; k3++)
            xs += diffLDS[base + k3][c] * pLDS[base + k3];
        xsum[(size_t)((e_base + el) * 4 + uu2) * 3 + c] = xs;
    }
}

// ---------------- coordinate update (CSR gather of xsum) ----------------

__global__ void k_xupd(const float* __restrict__ xcur, const float* __restrict__ xsum,
                       const int* __restrict__ offB, const int* __restrict__ listE,
                       float* __restrict__ xnext)
{
    int i = blockIdx.x * 256 + threadIdx.x;
    if (i >= NATOM * 3) return;
    int a = i / 3, d = i - a * 3;
    int b = a >> 2, u = a & 3;
    int o0 = offB[b], o1 = offB[b + 1];
    float xs = 0.f;
    for (int pos = o0; pos < o1; pos++) {
        int e = listE[pos];
        xs += xsum[(size_t)(e * 4 + u) * 3 + d];
    }
    int deg = o1 - o0;
    xnext[i] = xcur[i] + ((deg > 0) ? xs / (3.0f * (float)deg) : 0.f);
}

// ---------------- fused node MLP (gathers msum directly; hybrid-precision MFMA) ----------------

__global__ __launch_bounds__(256, 4) void k_node(
    unsigned short* __restrict__ hHI,
    unsigned short* __restrict__ hLO,
    const unsigned short* __restrict__ msum,
    const int* __restrict__ offB,
    const int* __restrict__ listE,
    const unsigned short* __restrict__ n1f_hi, const unsigned short* __restrict__ n1f_lo,
    const unsigned short* __restrict__ n2f_hi, const unsigned short* __restrict__ n2f_lo,
    const float* __restrict__ nb1,
    const float* __restrict__ nb2)
{
    __shared__ unsigned short wbufH[4096], wbufL[4096];
    __shared__ unsigned short hid[4][16 * 128];

    const int tid = threadIdx.x;
    const int wid = tid >> 6, l = tid & 63;
    const int g = l >> 4, er = l & 15;
    const int a0 = blockIdx.x * 64 + wid * 16;
    const int a = a0 + er;
    const int b = a >> 2, u = a & 3;
    const int o0 = offB[b], o1 = offB[b + 1];

    const int goff = wid * 512 + l * 8;
    unsigned short* lb0H = wbufH + wid * 512;
    unsigned short* lb1H = wbufH + 2048 + wid * 512;
    unsigned short* lb0L = wbufL + wid * 512;
    unsigned short* lb1L = wbufL + 2048 + wid * 512;

    // ---- phase A: hid = silu([h|agg] @ W1 + b1), K=256, 3-MFMA split ----
    {
        f32x4 acc[8];
        #pragma unroll
        for (int jj = 0; jj < 8; jj++) acc[jj] = (f32x4){0.f, 0.f, 0.f, 0.f};

        #pragma unroll 1
        for (int kb = 0; kb < 8; kb++) {
            __syncthreads();
            stage16(n1f_hi + (kb << 12) + goff,        lb0H);
            stage16(n1f_hi + (kb << 12) + 2048 + goff, lb1H);
            stage16(n1f_lo + (kb << 12) + goff,        lb0L);
            stage16(n1f_lo + (kb << 12) + 2048 + goff, lb1L);
            bf16x8 ah, al;
            if (kb < 4) {
                const size_t off = (size_t)a * 128 + kb * 32 + g * 8;
                ah = *(const bf16x8*)(hHI + off);
                al = *(const bf16x8*)(hLO + off);
            } else {
                float s[8];
                #pragma unroll
                for (int q = 0; q < 8; q++) s[q] = 0.f;
                for (int pos = o0; pos < o1; pos++) {
                    const int e = listE[pos];
                    bf16x8 mv = *(const bf16x8*)(msum + (size_t)(e * 4 + u) * 128 + (kb - 4) * 32 + g * 8);
                    #pragma unroll
                    for (int q = 0; q < 8; q++) s[q] += bf2f((unsigned short)mv[q]);
                }
                #pragma unroll
                for (int q = 0; q < 8; q++) { unsigned short hh, ll; csplit(s[q], hh, ll); ah[q] = (short)hh; al[q] = (short)ll; }
            }
            __syncthreads();
            __builtin_amdgcn_s_setprio(1);
            #pragma unroll
            for (int jj = 0; jj < 8; jj++) {
                const int off = (jj << 9) + (l << 3);
                bf16x8 wh = *(const bf16x8*)&wbufH[off];
                bf16x8 wl = *(const bf16x8*)&wbufL[off];
                acc[jj] = __builtin_amdgcn_mfma_f32_16x16x32_bf16(ah, wh, acc[jj], 0, 0, 0);
                acc[jj] = __builtin_amdgcn_mfma_f32_16x16x32_bf16(al, wh, acc[jj], 0, 0, 0);
                acc[jj] = __builtin_amdgcn_mfma_f32_16x16x32_bf16(ah, wl, acc[jj], 0, 0, 0);
            }
            __builtin_amdgcn_s_setprio(0);
        }
        #pragma unroll
        for (int jp = 0; jp < 4; jp++) {
            const int n0 = (jp * 2) * 16 + er, n1 = n0 + 16;
            const float b0 = nb1[n0], b1 = nb1[n1];
            #pragma unroll
            for (int reg = 0; reg < 4; reg++) {
                const int row = g * 4 + reg;
                float v0 = silu_f(acc[jp*2][reg] + b0);
                float v1 = silu_f(acc[jp*2+1][reg] + b1);
                unsigned int pk = cvtpk2(v0, v1);
                const int m = (row & 7) << 3;
                hid[wid][row * 128 + (n0 ^ m)] = (unsigned short)pk;
                hid[wid][row * 128 + (n1 ^ m)] = (unsigned short)(pk >> 16);
            }
        }
    }

    // ---- phase B: h += hid @ W2 + b2, K=128, 2-MFMA ----
    {
        f32x4 acc[8];
        #pragma unroll
        for (int jj = 0; jj < 8; jj++) acc[jj] = (f32x4){0.f, 0.f, 0.f, 0.f};

        #pragma unroll 1
        for (int kb = 0; kb < 4; kb++) {
            __syncthreads();
            stage16(n2f_hi + (kb << 12) + goff,        lb0H);
            stage16(n2f_hi + (kb << 12) + 2048 + goff, lb1H);
            stage16(n2f_lo + (kb << 12) + goff,        lb0L);
            stage16(n2f_lo + (kb << 12) + 2048 + goff, lb1L);
            const int aoff = er * 128 + ((kb * 32 + g * 8) ^ ((er & 7) << 3));
            bf16x8 ab = *(const bf16x8*)&hid[wid][aoff];
            __syncthreads();
            __builtin_amdgcn_s_setprio(1);
            #pragma unroll
            for (int jj = 0; jj < 8; jj++) {
                const int off = (jj << 9) + (l << 3);
                bf16x8 wh = *(const bf16x8*)&wbufH[off];
                bf16x8 wl = *(const bf16x8*)&wbufL[off];
                acc[jj] = __builtin_amdgcn_mfma_f32_16x16x32_bf16(ab, wh, acc[jj], 0, 0, 0);
                acc[jj] = __builtin_amdgcn_mfma_f32_16x16x32_bf16(ab, wl, acc[jj], 0, 0, 0);
            }
            __builtin_amdgcn_s_setprio(0);
        }
        #pragma unroll
        for (int jj = 0; jj < 8; jj++) {
            const int n = jj * 16 + er;
            const float bv = nb2[n];
            #pragma unroll
            for (int reg = 0; reg < 4; reg++) {
                const int row = g * 4 + reg;
                const size_t idx = (size_t)(a0 + row) * 128 + n;
                float v = acc[jj][reg] + bv + bf2f(hHI[idx]) + bf2f(hLO[idx]);
                unsigned short hh, ll; csplit(v, hh, ll);
                hHI[idx] = hh;
                hLO[idx] = ll;
            }
        }
    }
}

// ---------------- generic tiled f32 GEMM (emb MLPs; plane in/out variants) ----------------

template<bool PLANEIN, bool PLANEOUT>
__global__ __launch_bounds__(128) void k_gemm(
    const float* __restrict__ A0,
    const unsigned short* __restrict__ AHI, const unsigned short* __restrict__ ALO,
    const float* __restrict__ W, const float* __restrict__ bias,
    float* __restrict__ C,
    unsigned short* __restrict__ CHI, unsigned short* __restrict__ CLO, int M)
{
    __shared__ float At[128][32];
    __shared__ float Bs[32][128];
    const int tid = threadIdx.x;
    const int tile0 = blockIdx.x * 32;
    const int r = tid >> 2, part = tid & 3;
    const int gr = tile0 + r;

    if (gr < M) {
        #pragma unroll
        for (int j = 0; j < 8; j++) {
            int c = part * 32 + j * 4;
            float f0, f1, f2, f3;
            if (PLANEIN) {
                ushort4 vh = *(const ushort4*)(AHI + (size_t)gr * 128 + c);
                ushort4 vl = *(const ushort4*)(ALO + (size_t)gr * 128 + c);
                f0 = bf2f(vh.x) + bf2f(vl.x);
                f1 = bf2f(vh.y) + bf2f(vl.y);
                f2 = bf2f(vh.z) + bf2f(vl.z);
                f3 = bf2f(vh.w) + bf2f(vl.w);
            } else {
                float4 v = *(const float4*)(A0 + (size_t)gr * 128 + c);
                f0 = v.x; f1 = v.y; f2 = v.z; f3 = v.w;
            }
            At[c][r] = f0; At[c+1][r] = f1; At[c+2][r] = f2; At[c+3][r] = f3;
        }
    } else {
        #pragma unroll
        for (int j = 0; j < 8; j++) {
            int c = part * 32 + j * 4;
            At[c][r] = 0.f; At[c+1][r] = 0.f; At[c+2][r] = 0.f; At[c+3][r] = 0.f;
        }
    }

    float acc[4][8];
    #pragma unroll
    for (int i = 0; i < 4; i++)
        #pragma unroll
        for (int j = 0; j < 8; j++) acc[i][j] = 0.f;

    const int tx = tid & 15, ty = tid >> 4;

    for (int kb = 0; kb < 4; kb++) {
        __syncthreads();
        #pragma unroll
        for (int j = 0; j < 8; j++) {
            int li = j * 512 + tid * 4;
            int kk = li >> 7, c = li & 127;
            float4 v = *(const float4*)(W + (size_t)(kb * 32 + kk) * 128 + c);
            *(float4*)&Bs[kk][c] = v;
        }
        __syncthreads();
        #pragma unroll 8
        for (int kk = 0; kk < 32; kk++) {
            float4 a  = *(const float4*)&At[kb * 32 + kk][ty * 4];
            float4 b0 = *(const float4*)&Bs[kk][tx * 8];
            float4 b1 = *(const float4*)&Bs[kk][tx * 8 + 4];
            float av[4] = {a.x, a.y, a.z, a.w};
            float bv[8] = {b0.x, b0.y, b0.z, b0.w, b1.x, b1.y, b1.z, b1.w};
            #pragma unroll
            for (int i = 0; i < 4; i++)
                #pragma unroll
                for (int j = 0; j < 8; j++)
                    acc[i][j] = fmaf(av[i], bv[j], acc[i][j]);
        }
    }

    #pragma unroll
    for (int i = 0; i < 4; i++) {
        int grr = tile0 + ty * 4 + i;
        if (grr >= M) continue;
        #pragma unroll
        for (int j = 0; j < 8; j++) {
            int c = tx * 8 + j;
            float v = acc[i][j] + bias[c];
            if (PLANEOUT) {
                unsigned short hh, ll; csplit(v, hh, ll);
                CHI[(size_t)grr * 128 + c] = hh;
                CLO[(size_t)grr * 128 + c] = ll;
            } else {
                C[(size_t)grr * 128 + c] = v;
            }
        }
    }
}

// ---------------- launch ----------------

extern "C" void kernel_launch(void* const* d_in, const int* in_sizes, int n_in,
                              void* d_out, int out_size, void* d_ws, size_t ws_size,
                              hipStream_t stream) {
    const float* H        = (const float*)d_in[0];
    const float* Z        = (const float*)d_in[1];
    const int*   edges    = (const int*)  d_in[4];
    const float* eattr    = (const float*)d_in[5];
    const float* emb_in_w = (const float*)d_in[6];
    const float* emb_in_b = (const float*)d_in[7];
    const float* emb_out_w= (const float*)d_in[8];
    const float* emb_out_b= (const float*)d_in[9];
    const float* edge_w1  = (const float*)d_in[10];
    const float* edge_b1  = (const float*)d_in[11];
    const float* edge_w2  = (const float*)d_in[12];
    const float* edge_b2  = (const float*)d_in[13];
    const float* node_w1  = (const float*)d_in[14];
    const float* node_b1  = (const float*)d_in[15];
    const float* node_w2  = (const float*)d_in[16];
    const float* node_b2  = (const float*)d_in[17];
    const float* coord_w1 = (const float*)d_in[18];
    const float* coord_b1 = (const float*)d_in[19];
    const float* coord_w2 = (const float*)d_in[20];

    float* out  = (float*)d_out;
    float* hbuf = out;                              // [N][128] f32 (final output only)
    float* xout = out + (size_t)NATOM * 128;        // [N][3]

    // workspace (~78 MB), 16B-aligned sections
    char* w = (char*)d_ws;
    unsigned short* hHI = (unsigned short*)w;  w += (size_t)NATOM * 128 * 2;  // 20.48 MB
    unsigned short* hLO = (unsigned short*)w;  w += (size_t)NATOM * 128 * 2;  // 20.48 MB
    unsigned short* msum = (unsigned short*)w; w += (size_t)NGRP * 128 * 2;   // 30.72 MB
    float* xsum = (float*)w;           w += (size_t)NGRP * 3 * 4;             // 1.44 MB
    float* xA  = (float*)w;            w += (size_t)NATOM * 3 * 4;
    float* xB  = (float*)w;            w += (size_t)NATOM * 3 * 4;
    unsigned short* w1f_hi = (unsigned short*)w;  w += (size_t)3 * W1F_L * 2;
    unsigned short* w1f_lo = (unsigned short*)w;  w += (size_t)3 * W1F_L * 2;
    unsigned short* w2f_hi = (unsigned short*)w;  w += (size_t)3 * W2F_L * 2;
    unsigned short* w2f_lo = (unsigned short*)w;  w += (size_t)3 * W2F_L * 2;
    unsigned short* c1f_hi = (unsigned short*)w;  w += (size_t)3 * W2F_L * 2;
    unsigned short* c1f_lo = (unsigned short*)w;  w += (size_t)3 * W2F_L * 2;
    unsigned short* n1f_hi = (unsigned short*)w;  w += (size_t)3 * NW1F_L * 2;
    unsigned short* n1f_lo = (unsigned short*)w;  w += (size_t)3 * NW1F_L * 2;
    unsigned short* n2f_hi = (unsigned short*)w;  w += (size_t)3 * W2F_L * 2;
    unsigned short* n2f_lo = (unsigned short*)w;  w += (size_t)3 * W2F_L * 2;
    int* colIdx = (int*)w;             w += (size_t)EALL * 4;
    int* degB   = (int*)w;             w += (size_t)NBLK * 4;
    int* cursor = (int*)w;             w += (size_t)NBLK * 4;
    int* listE  = (int*)w;             w += (size_t)EBK * 4;
    int* offB   = (int*)w;             w += (size_t)(NBLK + 1) * 4;

    hipMemsetAsync(degB,   0, NBLK * sizeof(int), stream);
    hipMemsetAsync(cursor, 0, NBLK * sizeof(int), stream);

    k_count<<<(EBK + 255) / 256, 256, 0, stream>>>(edges, degB);
    k_scan <<<1, 1024, 0, stream>>>(degB, offB);
    k_fill <<<(EBK + 255) / 256, 256, 0, stream>>>(edges, offB, cursor, listE);
    k_topk <<<(EBK * UU + 255) / 256, 256, 0, stream>>>(edges, Z, colIdx);

    {
        int total = 3 * W1F_L + 3 * W2F_L + 3 * W2F_L + 3 * NW1F_L + 3 * W2F_L;
        k_wfrag<<<(total + 255) / 256, 256, 0, stream>>>(
            edge_w1, edge_w2, coord_w1, node_w1, node_w2,
            w1f_hi, w1f_lo, w2f_hi, w2f_lo, c1f_hi, c1f_lo,
            n1f_hi, n1f_lo, n2f_hi, n2f_lo);
    }

    // h = H @ emb_in_w + b  (write hi/lo planes)
    k_gemm<false, true><<<NATOM / 32, 128, 0, stream>>>(
        H, nullptr, nullptr, emb_in_w, emb_in_b, nullptr, hHI, hLO, NATOM);

    const float* xcur = Z;
    for (int l = 0; l < LAY; l++) {
        float* xnext = (l == 0) ? xA : (l == 1) ? xB : xout;

        k_edge_flat<<<EBK / E_WG, 768, 0, stream>>>(
            hHI, hLO, xcur, eattr, edges, colIdx,
            w1f_hi + (size_t)l * W1F_L, w1f_lo + (size_t)l * W1F_L,
            w2f_hi + (size_t)l * W2F_L, w2f_lo + (size_t)l * W2F_L,
            c1f_hi + (size_t)l * W2F_L, c1f_lo + (size_t)l * W2F_L,
            edge_b1 + l * 128, edge_b2 + l * 128, coord_b1 + l * 128, coord_w2 + l * 128,
            msum, xsum);

        k_xupd<<<(NATOM * 3 + 255) / 256, 256, 0, stream>>>(xcur, xsum, offB, listE, xnext);

        k_node<<<NATOM / 64, 256, 0, stream>>>(
            hHI, hLO, msum, offB, listE,
            n1f_hi + (size_t)l * NW1F_L, n1f_lo + (size_t)l * NW1F_L,
            n2f_hi + (size_t)l * W2F_L, n2f_lo + (size_t)l * W2F_L,
            node_b1 + l * 128, node_b2 + l * 128);

        xcur = xnext;
    }

    // h_out = h @ emb_out_w + b  (read planes, write f32 to d_out)
    k_gemm<true, false><<<NATOM / 32, 128, 0, stream>>>(
        nullptr, hHI, hLO, emb_out_w, emb_out_b, hbuf, nullptr, nullptr, NATOM);
}

// Round 13
// 892.069 us; speedup vs baseline: 1.0298x; 1.0298x over previous
//
#include <hip/hip_runtime.h>
#include <math.h>

#define HIDC 128
#define EDGEF 16
#define LAY 3
#define KNN 3
#define UU 4
#define NBLK 20000
#define NATOM (NBLK*UU)      // 80000
#define EBK 30000
#define EALL (EBK*UU*KNN)    // 360000
#define NGRP (EBK*UU)        // 120000 (edge,u) groups

#define W1F_L 36864          // 9 kb * 8 j * 64 lanes * 8
#define W2F_L 16384          // 4 kb * 8 j * 64 lanes * 8
#define NW1F_L 32768         // 8 kb * 8 j * 64 lanes * 8

#define E_WG 16              // block-edges per edge-kernel workgroup
#define ROWS_WG (E_WG*12)    // 192 rows
#define NODE_ROWS 192        // atoms per node-kernel workgroup

typedef __attribute__((ext_vector_type(8))) short bf16x8;
typedef __attribute__((ext_vector_type(4))) float f32x4;

__device__ __forceinline__ float silu_f(float v) {
    return __fdividef(v, 1.0f + __expf(-v));
}

__device__ __forceinline__ unsigned short f2bf(float f) {
    union { float f; unsigned int u; } v; v.f = f;
    unsigned int r = v.u + 0x7FFFu + ((v.u >> 16) & 1u);
    return (unsigned short)(r >> 16);
}

__device__ __forceinline__ float bf2f(unsigned short h) {
    union { unsigned int u; float f; } t; t.u = ((unsigned int)h) << 16;
    return t.f;
}

// full-precision split (RNE hi) — one-time weight prep only
__device__ __forceinline__ void split2(float v, short& hi, short& lo) {
    unsigned short h = f2bf(v);
    hi = (short)h;
    lo = (short)f2bf(v - bf2f(h));
}

// cheap split: truncated hi + RNE lo (lo captures truncation exactly; ~2^-17 rel)
__device__ __forceinline__ void csplit(float v, unsigned short& hi, unsigned short& lo) {
    unsigned int hu = __float_as_uint(v) & 0xffff0000u;
    hi = (unsigned short)(hu >> 16);
    lo = f2bf(v - __uint_as_float(hu));
}

// packed bf16 pair conversion: low16 = bf16(a), high16 = bf16(b)  [T12 recipe]
__device__ __forceinline__ unsigned int cvtpk2(float a, float b) {
    unsigned int r;
    asm("v_cvt_pk_bf16_f32 %0, %1, %2" : "=v"(r) : "v"(a), "v"(b));
    return r;
}

// async global->LDS DMA: 16B per lane, LDS dest = wave-uniform base + lane*16
__device__ __forceinline__ void stage16(const unsigned short* gsrc, unsigned short* ldst) {
    __builtin_amdgcn_global_load_lds(
        (const __attribute__((address_space(1))) unsigned int*)(const void*)gsrc,
        (__attribute__((address_space(3))) unsigned int*)(void*)ldst,
        16, 0, 0);
}

// ---------------- CSR build ----------------

__global__ void k_count(const int* __restrict__ edges, int* __restrict__ degB) {
    int e = blockIdx.x * 256 + threadIdx.x;
    if (e < EBK) atomicAdd(&degB[edges[e]], 1);
}

__global__ void k_scan(const int* __restrict__ degB, int* __restrict__ offB) {
    __shared__ int s[1024];
    __shared__ int carry;
    if (threadIdx.x == 0) carry = 0;
    __syncthreads();
    for (int base = 0; base < NBLK; base += 1024) {
        int i = base + threadIdx.x;
        int v = (i < NBLK) ? degB[i] : 0;
        s[threadIdx.x] = v;
        __syncthreads();
        for (int d = 1; d < 1024; d <<= 1) {
            int t = (threadIdx.x >= d) ? s[threadIdx.x - d] : 0;
            __syncthreads();
            s[threadIdx.x] += t;
            __syncthreads();
        }
        if (i < NBLK) offB[i] = carry + s[threadIdx.x] - v;
        int tot = s[1023];
        __syncthreads();
        if (threadIdx.x == 0) carry += tot;
        __syncthreads();
    }
    if (threadIdx.x == 0) offB[NBLK] = carry;
}

__global__ void k_fill(const int* __restrict__ edges, const int* __restrict__ offB,
                       int* __restrict__ cursor, int* __restrict__ listE) {
    int e = blockIdx.x * 256 + threadIdx.x;
    if (e < EBK) {
        int b = edges[e];
        int p = atomicAdd(&cursor[b], 1);
        listE[offB[b] + p] = e;
    }
}

// top-3 nearest dst atoms per src atom; exact f32, tie -> lower index (matches top_k)
__global__ void k_topk(const int* __restrict__ edges, const float* __restrict__ Z,
                       int* __restrict__ colIdx) {
    int t = blockIdx.x * 256 + threadIdx.x;
    if (t >= EBK * UU) return;
    int e = t >> 2, u = t & 3;
    int b0 = edges[e], b1 = edges[EBK + e];
    int s = b0 * UU + u;
    float zs0 = Z[s*3+0], zs1 = Z[s*3+1], zs2 = Z[s*3+2];
    float d2[UU];
    #pragma unroll
    for (int v = 0; v < UU; v++) {
        int d = b1 * UU + v;
        float a0 = __fsub_rn(zs0, Z[d*3+0]);
        float a1 = __fsub_rn(zs1, Z[d*3+1]);
        float a2 = __fsub_rn(zs2, Z[d*3+2]);
        float p0 = __fmul_rn(a0, a0);
        float p1 = __fmul_rn(a1, a1);
        float p2 = __fmul_rn(a2, a2);
        d2[v] = __fadd_rn(__fadd_rn(p0, p1), p2);
    }
    bool used[UU] = {false, false, false, false};
    #pragma unroll
    for (int k = 0; k < KNN; k++) {
        int best = -1;
        float bd = INFINITY;
        #pragma unroll
        for (int v = 0; v < UU; v++) {
            if (!used[v] && d2[v] < bd) { bd = d2[v]; best = v; }
        }
        used[best] = true;
        colIdx[t * KNN + k] = b1 * UU + best;
    }
}

// ---------------- weight fragment precompute (hi/lo bf16, MFMA B-layout) ----------------

__global__ void k_wfrag(const float* __restrict__ ew1, const float* __restrict__ ew2,
                        const float* __restrict__ cw1,
                        const float* __restrict__ nw1, const float* __restrict__ nw2,
                        unsigned short* __restrict__ w1f_hi, unsigned short* __restrict__ w1f_lo,
                        unsigned short* __restrict__ w2f_hi, unsigned short* __restrict__ w2f_lo,
                        unsigned short* __restrict__ c1f_hi, unsigned short* __restrict__ c1f_lo,
                        unsigned short* __restrict__ n1f_hi, unsigned short* __restrict__ n1f_lo,
                        unsigned short* __restrict__ n2f_hi, unsigned short* __restrict__ n2f_lo) {
    int i = blockIdx.x * 256 + threadIdx.x;
    float v = 0.f;
    unsigned short* dh = nullptr;
    unsigned short* dl = nullptr;
    int di = 0;
    if (i < 3 * W1F_L) {
        int l = i / W1F_L, rem = i % W1F_L;
        int chunk = rem >> 9, lane = (rem >> 3) & 63, t = rem & 7;
        int kb = chunk >> 3, j = chunk & 7;
        int k = kb*32 + (lane >> 4)*8 + t, n = j*16 + (lane & 15);
        v = (k < 273) ? ew1[(size_t)l*273*128 + (size_t)k*128 + n] : 0.f;
        dh = w1f_hi; dl = w1f_lo; di = i;
    } else {
        int i2 = i - 3 * W1F_L;
        if (i2 < 3 * W2F_L) {
            int l = i2 / W2F_L, rem = i2 % W2F_L;
            int chunk = rem >> 9, lane = (rem >> 3) & 63, t = rem & 7;
            int kb = chunk >> 3, j = chunk & 7;
            int k = kb*32 + (lane >> 4)*8 + t, n = j*16 + (lane & 15);
            v = ew2[(size_t)l*128*128 + (size_t)k*128 + n];
            dh = w2f_hi; dl = w2f_lo; di = i2;
        } else {
            int i3 = i2 - 3 * W2F_L;
            if (i3 < 3 * W2F_L) {
                int l = i3 / W2F_L, rem = i3 % W2F_L;
                int chunk = rem >> 9, lane = (rem >> 3) & 63, t = rem & 7;
                int kb = chunk >> 3, j = chunk & 7;
                int k = kb*32 + (lane >> 4)*8 + t, n = j*16 + (lane & 15);
                v = cw1[(size_t)l*128*128 + (size_t)k*128 + n];
                dh = c1f_hi; dl = c1f_lo; di = i3;
            } else {
                int i4 = i3 - 3 * W2F_L;
                if (i4 < 3 * NW1F_L) {
                    int l = i4 / NW1F_L, rem = i4 % NW1F_L;
                    int chunk = rem >> 9, lane = (rem >> 3) & 63, t = rem & 7;
                    int kb = chunk >> 3, j = chunk & 7;
                    int k = kb*32 + (lane >> 4)*8 + t, n = j*16 + (lane & 15);
                    v = nw1[(size_t)l*256*128 + (size_t)k*128 + n];
                    dh = n1f_hi; dl = n1f_lo; di = i4;
                } else {
                    int i5 = i4 - 3 * NW1F_L;
                    if (i5 >= 3 * W2F_L) return;
                    int l = i5 / W2F_L, rem = i5 % W2F_L;
                    int chunk = rem >> 9, lane = (rem >> 3) & 63, t = rem & 7;
                    int kb = chunk >> 3, j = chunk & 7;
                    int k = kb*32 + (lane >> 4)*8 + t, n = j*16 + (lane & 15);
                    v = nw2[(size_t)l*128*128 + (size_t)k*128 + n];
                    dh = n2f_hi; dl = n2f_lo; di = i5;
                }
            }
        }
    }
    short hi, lo;
    split2(v, hi, lo);
    dh[di] = (unsigned short)hi;
    dl[di] = (unsigned short)lo;
}

// ---------------- flat-12 fused edge pipeline (hybrid-precision MFMA) ----------------
// (unchanged from round 12 — proven at 215 us)

__global__ __launch_bounds__(768, 6) void k_edge_flat(
    const unsigned short* __restrict__ hHI,
    const unsigned short* __restrict__ hLO,
    const float* __restrict__ x,
    const float* __restrict__ eattr,
    const int* __restrict__ edges0,
    const int* __restrict__ colIdx,
    const unsigned short* __restrict__ w1f_hi, const unsigned short* __restrict__ w1f_lo,
    const unsigned short* __restrict__ w2f_hi, const unsigned short* __restrict__ w2f_lo,
    const unsigned short* __restrict__ c1f_hi, const unsigned short* __restrict__ c1f_lo,
    const float* __restrict__ eb1,
    const float* __restrict__ eb2,
    const float* __restrict__ cb1,
    const float* __restrict__ cw2v,
    unsigned short* __restrict__ msum,
    float* __restrict__ xsum)
{
    __shared__ unsigned short wbufH[4096], wbufL[4096];        // 16 KB
    __shared__ unsigned short Mlds[ROWS_WG * 128];             // 48 KB (C1, then M)
    __shared__ float diffLDS[ROWS_WG][3];                      // 2.25 KB
    __shared__ float pLDS[ROWS_WG];                            // 0.75 KB

    const int tid = threadIdx.x;
    const int wid = tid >> 6, l = tid & 63;
    const int g = l >> 4, er = l & 15;
    const int e_base = blockIdx.x * E_WG;
    const int r0 = wid * 16;

    const int row_g = r0 + er;
    const int e_loc = row_g / 12;
    const int rr = row_g - e_loc * 12;
    const int u = rr / 3;
    const int kk = rr - u * 3;
    const int e = e_base + e_loc;
    const int bs = edges0[e];
    const int srcA = bs * 4 + u;
    const int colA = colIdx[(e * 4 + u) * 3 + kk];
    float rad = 0.f;
    if (g == 0) {
        float dx = x[srcA*3+0] - x[colA*3+0];
        float dy = x[srcA*3+1] - x[colA*3+1];
        float dz = x[srcA*3+2] - x[colA*3+2];
        rad = dx*dx + dy*dy + dz*dz;
        diffLDS[row_g][0] = dx; diffLDS[row_g][1] = dy; diffLDS[row_g][2] = dz;
    }

    const int goff = wid * 512 + l * 8;
    unsigned short* lb0H = wbufH + wid * 512;
    unsigned short* lb1H = wbufH + 2048 + wid * 512;
    unsigned short* lb0L = wbufL + wid * 512;
    unsigned short* lb1L = wbufL + 2048 + wid * 512;

    // ---- phase 1 ----
    {
        f32x4 acc[8];
        #pragma unroll
        for (int jj = 0; jj < 8; jj++) acc[jj] = (f32x4){0.f, 0.f, 0.f, 0.f};

        #pragma unroll 1
        for (int kb = 0; kb < 9; kb++) {
            __syncthreads();
            if (wid < 4) {
                stage16(w1f_hi + (kb << 12) + goff,        lb0H);
                stage16(w1f_hi + (kb << 12) + 2048 + goff, lb1H);
                stage16(w1f_lo + (kb << 12) + goff,        lb0L);
                stage16(w1f_lo + (kb << 12) + 2048 + goff, lb1L);
            }
            bf16x8 ah, al;
            if (kb < 8) {
                const size_t off = (kb < 4) ? ((size_t)srcA * 128 + kb * 32 + g * 8)
                                            : ((size_t)colA * 128 + (kb - 4) * 32 + g * 8);
                ah = *(const bf16x8*)(hHI + off);
                al = *(const bf16x8*)(hLO + off);
            } else {
                float tv[8];
                #pragma unroll
                for (int q = 0; q < 8; q++) tv[q] = 0.f;
                if (g == 0) {
                    tv[0] = rad;
                    #pragma unroll
                    for (int q = 1; q < 8; q++) tv[q] = eattr[(size_t)e*16 + (q-1)];
                } else if (g == 1) {
                    #pragma unroll
                    for (int q = 0; q < 8; q++) tv[q] = eattr[(size_t)e*16 + 7 + q];
                } else if (g == 2) {
                    tv[0] = eattr[(size_t)e*16 + 15];
                }
                #pragma unroll
                for (int q = 0; q < 8; q++) { unsigned short hh, ll; csplit(tv[q], hh, ll); ah[q] = (short)hh; al[q] = (short)ll; }
            }
            __syncthreads();
            __builtin_amdgcn_s_setprio(1);
            #pragma unroll
            for (int jj = 0; jj < 8; jj++) {
                const int off = (jj << 9) + (l << 3);
                bf16x8 wh = *(const bf16x8*)&wbufH[off];
                bf16x8 wl = *(const bf16x8*)&wbufL[off];
                acc[jj] = __builtin_amdgcn_mfma_f32_16x16x32_bf16(ah, wh, acc[jj], 0, 0, 0);
                acc[jj] = __builtin_amdgcn_mfma_f32_16x16x32_bf16(al, wh, acc[jj], 0, 0, 0);
                acc[jj] = __builtin_amdgcn_mfma_f32_16x16x32_bf16(ah, wl, acc[jj], 0, 0, 0);
            }
            __builtin_amdgcn_s_setprio(0);
        }
        #pragma unroll
        for (int jp = 0; jp < 4; jp++) {
            const int n0 = (jp * 2) * 16 + er, n1 = n0 + 16;
            const float b0 = eb1[n0], b1 = eb1[n1];
            #pragma unroll
            for (int reg = 0; reg < 4; reg++) {
                const int row = r0 + g * 4 + reg;
                float v0 = silu_f(acc[jp*2][reg] + b0);
                float v1 = silu_f(acc[jp*2+1][reg] + b1);
                unsigned int pk = cvtpk2(v0, v1);
                const int m = (row & 7) << 3;
                Mlds[row * 128 + (n0 ^ m)] = (unsigned short)pk;
                Mlds[row * 128 + (n1 ^ m)] = (unsigned short)(pk >> 16);
            }
        }
    }

    // ---- phase 2 ----
    {
        f32x4 acc[8];
        #pragma unroll
        for (int jj = 0; jj < 8; jj++) acc[jj] = (f32x4){0.f, 0.f, 0.f, 0.f};

        #pragma unroll 1
        for (int kb = 0; kb < 4; kb++) {
            __syncthreads();
            if (wid < 4) {
                stage16(w2f_hi + (kb << 12) + goff,        lb0H);
                stage16(w2f_hi + (kb << 12) + 2048 + goff, lb1H);
                stage16(w2f_lo + (kb << 12) + goff,        lb0L);
                stage16(w2f_lo + (kb << 12) + 2048 + goff, lb1L);
            }
            const int aoff = row_g * 128 + ((kb * 32 + g * 8) ^ ((row_g & 7) << 3));
            bf16x8 a2 = *(const bf16x8*)&Mlds[aoff];
            __syncthreads();
            __builtin_amdgcn_s_setprio(1);
            #pragma unroll
            for (int jj = 0; jj < 8; jj++) {
                const int off = (jj << 9) + (l << 3);
                bf16x8 wh = *(const bf16x8*)&wbufH[off];
                bf16x8 wl = *(const bf16x8*)&wbufL[off];
                acc[jj] = __builtin_amdgcn_mfma_f32_16x16x32_bf16(a2, wh, acc[jj], 0, 0, 0);
                acc[jj] = __builtin_amdgcn_mfma_f32_16x16x32_bf16(a2, wl, acc[jj], 0, 0, 0);
            }
            __builtin_amdgcn_s_setprio(0);
        }
        #pragma unroll
        for (int jp = 0; jp < 4; jp++) {
            const int n0 = (jp * 2) * 16 + er, n1 = n0 + 16;
            const float b0 = eb2[n0], b1 = eb2[n1];
            #pragma unroll
            for (int reg = 0; reg < 4; reg++) {
                const int row = r0 + g * 4 + reg;
                float v0 = silu_f(acc[jp*2][reg] + b0);
                float v1 = silu_f(acc[jp*2+1][reg] + b1);
                unsigned int pk = cvtpk2(v0, v1);
                const int m = (row & 7) << 3;
                Mlds[row * 128 + (n0 ^ m)] = (unsigned short)pk;
                Mlds[row * 128 + (n1 ^ m)] = (unsigned short)(pk >> 16);
            }
        }
    }

    // ---- phase 3 ----
    {
        f32x4 acc[8];
        #pragma unroll
        for (int jj = 0; jj < 8; jj++) acc[jj] = (f32x4){0.f, 0.f, 0.f, 0.f};

        #pragma unroll 1
        for (int kb = 0; kb < 4; kb++) {
            __syncthreads();
            if (wid < 4) {
                stage16(c1f_hi + (kb << 12) + goff,        lb0H);
                stage16(c1f_hi + (kb << 12) + 2048 + goff, lb1H);
                stage16(c1f_lo + (kb << 12) + goff,        lb0L);
                stage16(c1f_lo + (kb << 12) + 2048 + goff, lb1L);
            }
            const int aoff = row_g * 128 + ((kb * 32 + g * 8) ^ ((row_g & 7) << 3));
            bf16x8 a3 = *(const bf16x8*)&Mlds[aoff];
            __syncthreads();
            __builtin_amdgcn_s_setprio(1);
            #pragma unroll
            for (int jj = 0; jj < 8; jj++) {
                const int off = (jj << 9) + (l << 3);
                bf16x8 wh = *(const bf16x8*)&wbufH[off];
                bf16x8 wl = *(const bf16x8*)&wbufL[off];
                acc[jj] = __builtin_amdgcn_mfma_f32_16x16x32_bf16(a3, wh, acc[jj], 0, 0, 0);
                acc[jj] = __builtin_amdgcn_mfma_f32_16x16x32_bf16(a3, wl, acc[jj], 0, 0, 0);
            }
            __builtin_amdgcn_s_setprio(0);
        }
        float p[4] = {0.f, 0.f, 0.f, 0.f};
        #pragma unroll
        for (int jj = 0; jj < 8; jj++) {
            const int n = jj * 16 + er;
            const float cb = cb1[n], cw = cw2v[n];
            #pragma unroll
            for (int reg = 0; reg < 4; reg++)
                p[reg] += silu_f(acc[jj][reg] + cb) * cw;
        }
        #pragma unroll
        for (int d = 1; d < 16; d <<= 1) {
            #pragma unroll
            for (int reg = 0; reg < 4; reg++)
                p[reg] += __shfl_xor(p[reg], d);
        }
        if (er == 0) {
            #pragma unroll
            for (int reg = 0; reg < 4; reg++)
                pLDS[r0 + g * 4 + reg] = p[reg];
        }
    }
    __syncthreads();

    // ---- merged tail: msum (u32 col-pairs) + xsum ----
    for (int t = tid; t < E_WG * 4 * 64; t += 768) {
        const int gi = t >> 6, cp = t & 63;
        const int c0 = cp * 2;
        const int el = gi >> 2, uu2 = gi & 3;
        const int base = el * 12 + uu2 * 3;
        float s0 = 0.f, s1 = 0.f;
        #pragma unroll
        for (int k3 = 0; k3 < 3; k3++) {
            const int row = base + k3;
            const int m = (row & 7) << 3;
            unsigned int pr = *(const unsigned int*)&Mlds[row * 128 + (c0 ^ m)];
            s0 += bf2f((unsigned short)(pr & 0xffffu));
            s1 += bf2f((unsigned short)(pr >> 16));
        }
        ((unsigned int*)msum)[(size_t)((e_base + el) * 4 + uu2) * 64 + cp] = cvtpk2(s0, s1);
    }
    if (tid < E_WG * 4 * 3) {
        const int gi = tid / 3, c = tid - gi * 3;
        const int el = gi >> 2, uu2 = gi & 3;
        const int base = el * 12 + uu2 * 3;
        float xs = 0.f;
        #pragma unroll
        for (int k3 = 0; k3 < 3; k3++)
            xs += diffLDS[base + k3][c] * pLDS[base + k3];
        xsum[(size_t)((e_base + el) * 4 + uu2) * 3 + c] = xs;
    }
}

// ---------------- coordinate update (CSR gather of xsum) ----------------

__global__ void k_xupd(const float* __restrict__ xcur, const float* __restrict__ xsum,
                       const int* __restrict__ offB, const int* __restrict__ listE,
                       float* __restrict__ xnext)
{
    int i = blockIdx.x * 256 + threadIdx.x;
    if (i >= NATOM * 3) return;
    int a = i / 3, d = i - a * 3;
    int b = a >> 2, u = a & 3;
    int o0 = offB[b], o1 = offB[b + 1];
    float xs = 0.f;
    for (int pos = o0; pos < o1; pos++) {
        int e = listE[pos];
        xs += xsum[(size_t)(e * 4 + u) * 3 + d];
    }
    int deg = o1 - o0;
    xnext[i] = xcur[i] + ((deg > 0) ? xs / (3.0f * (float)deg) : 0.f);
}

// ---------------- fused node MLP (12-wave shared weights; hybrid-precision MFMA) ----------------
// WG = 768 threads = 12 waves = 192 atoms. Weight chunks staged once per WG.
// h_new = h + silu([h|agg]@w1+b1)@w2+b2; agg gathered from msum via CSR on the fly.

__global__ __launch_bounds__(768, 6) void k_node(
    unsigned short* __restrict__ hHI,
    unsigned short* __restrict__ hLO,
    const unsigned short* __restrict__ msum,
    const int* __restrict__ offB,
    const int* __restrict__ listE,
    const unsigned short* __restrict__ n1f_hi, const unsigned short* __restrict__ n1f_lo,
    const unsigned short* __restrict__ n2f_hi, const unsigned short* __restrict__ n2f_lo,
    const float* __restrict__ nb1,
    const float* __restrict__ nb2)
{
    __shared__ unsigned short wbufH[4096], wbufL[4096];   // 16 KB
    __shared__ unsigned short hid[NODE_ROWS * 128];       // 48 KB

    const int tid = threadIdx.x;
    const int wid = tid >> 6, l = tid & 63;
    const int g = l >> 4, er = l & 15;
    const int r0 = wid * 16;
    const int row_g = r0 + er;
    const int a = blockIdx.x * NODE_ROWS + row_g;
    const bool aOK = (a < NATOM);
    const int aC = aOK ? a : 0;
    const int b = aC >> 2, u = aC & 3;
    const int o0 = aOK ? offB[b] : 0;
    const int o1 = aOK ? offB[b + 1] : 0;

    const int goff = wid * 512 + l * 8;    // valid for wid<4 staging
    unsigned short* lb0H = wbufH + wid * 512;
    unsigned short* lb1H = wbufH + 2048 + wid * 512;
    unsigned short* lb0L = wbufL + wid * 512;
    unsigned short* lb1L = wbufL + 2048 + wid * 512;

    // ---- phase A: hid = silu([h|agg] @ W1 + b1), K=256, 3-MFMA split ----
    {
        f32x4 acc[8];
        #pragma unroll
        for (int jj = 0; jj < 8; jj++) acc[jj] = (f32x4){0.f, 0.f, 0.f, 0.f};

        #pragma unroll 1
        for (int kb = 0; kb < 8; kb++) {
            __syncthreads();
            if (wid < 4) {
                stage16(n1f_hi + (kb << 12) + goff,        lb0H);
                stage16(n1f_hi + (kb << 12) + 2048 + goff, lb1H);
                stage16(n1f_lo + (kb << 12) + goff,        lb0L);
                stage16(n1f_lo + (kb << 12) + 2048 + goff, lb1L);
            }
            bf16x8 ah, al;
            if (kb < 4) {
                const size_t off = (size_t)aC * 128 + kb * 32 + g * 8;
                ah = *(const bf16x8*)(hHI + off);
                al = *(const bf16x8*)(hLO + off);
            } else {
                float s[8];
                #pragma unroll
                for (int q = 0; q < 8; q++) s[q] = 0.f;
                for (int pos = o0; pos < o1; pos++) {
                    const int e = listE[pos];
                    bf16x8 mv = *(const bf16x8*)(msum + (size_t)(e * 4 + u) * 128 + (kb - 4) * 32 + g * 8);
                    #pragma unroll
                    for (int q = 0; q < 8; q++) s[q] += bf2f((unsigned short)mv[q]);
                }
                #pragma unroll
                for (int q = 0; q < 8; q++) { unsigned short hh, ll; csplit(s[q], hh, ll); ah[q] = (short)hh; al[q] = (short)ll; }
            }
            __syncthreads();
            __builtin_amdgcn_s_setprio(1);
            #pragma unroll
            for (int jj = 0; jj < 8; jj++) {
                const int off = (jj << 9) + (l << 3);
                bf16x8 wh = *(const bf16x8*)&wbufH[off];
                bf16x8 wl = *(const bf16x8*)&wbufL[off];
                acc[jj] = __builtin_amdgcn_mfma_f32_16x16x32_bf16(ah, wh, acc[jj], 0, 0, 0);
                acc[jj] = __builtin_amdgcn_mfma_f32_16x16x32_bf16(al, wh, acc[jj], 0, 0, 0);
                acc[jj] = __builtin_amdgcn_mfma_f32_16x16x32_bf16(ah, wl, acc[jj], 0, 0, 0);
            }
            __builtin_amdgcn_s_setprio(0);
        }
        #pragma unroll
        for (int jp = 0; jp < 4; jp++) {
            const int n0 = (jp * 2) * 16 + er, n1 = n0 + 16;
            const float b0 = nb1[n0], b1 = nb1[n1];
            #pragma unroll
            for (int reg = 0; reg < 4; reg++) {
                const int row = r0 + g * 4 + reg;
                float v0 = silu_f(acc[jp*2][reg] + b0);
                float v1 = silu_f(acc[jp*2+1][reg] + b1);
                unsigned int pk = cvtpk2(v0, v1);
                const int m = (row & 7) << 3;
                hid[row * 128 + (n0 ^ m)] = (unsigned short)pk;
                hid[row * 128 + (n1 ^ m)] = (unsigned short)(pk >> 16);
            }
        }
    }

    // ---- phase B: h += hid @ W2 + b2, K=128, 2-MFMA ----
    {
        f32x4 acc[8];
        #pragma unroll
        for (int jj = 0; jj < 8; jj++) acc[jj] = (f32x4){0.f, 0.f, 0.f, 0.f};

        #pragma unroll 1
        for (int kb = 0; kb < 4; kb++) {
            __syncthreads();
            if (wid < 4) {
                stage16(n2f_hi + (kb << 12) + goff,        lb0H);
                stage16(n2f_hi + (kb << 12) + 2048 + goff, lb1H);
                stage16(n2f_lo + (kb << 12) + goff,        lb0L);
                stage16(n2f_lo + (kb << 12) + 2048 + goff, lb1L);
            }
            const int aoff = row_g * 128 + ((kb * 32 + g * 8) ^ ((row_g & 7) << 3));
            bf16x8 ab = *(const bf16x8*)&hid[aoff];
            __syncthreads();
            __builtin_amdgcn_s_setprio(1);
            #pragma unroll
            for (int jj = 0; jj < 8; jj++) {
                const int off = (jj << 9) + (l << 3);
                bf16x8 wh = *(const bf16x8*)&wbufH[off];
                bf16x8 wl = *(const bf16x8*)&wbufL[off];
                acc[jj] = __builtin_amdgcn_mfma_f32_16x16x32_bf16(ab, wh, acc[jj], 0, 0, 0);
                acc[jj] = __builtin_amdgcn_mfma_f32_16x16x32_bf16(ab, wl, acc[jj], 0, 0, 0);
            }
            __builtin_amdgcn_s_setprio(0);
        }
        #pragma unroll
        for (int jj = 0; jj < 8; jj++) {
            const int n = jj * 16 + er;
            const float bv = nb2[n];
            #pragma unroll
            for (int reg = 0; reg < 4; reg++) {
                const int row = r0 + g * 4 + reg;
                const int aw = blockIdx.x * NODE_ROWS + row;
                if (aw < NATOM) {
                    const size_t idx = (size_t)aw * 128 + n;
                    float v = acc[jj][reg] + bv + bf2f(hHI[idx]) + bf2f(hLO[idx]);
                    unsigned short hh, ll; csplit(v, hh, ll);
                    hHI[idx] = hh;
                    hLO[idx] = ll;
                }
            }
        }
    }
}

// ---------------- generic tiled f32 GEMM (emb MLPs; vectorized plane I/O) ----------------

template<bool PLANEIN, bool PLANEOUT>
__global__ __launch_bounds__(128) void k_gemm(
    const float* __restrict__ A0,
    const unsigned short* __restrict__ AHI, const unsigned short* __restrict__ ALO,
    const float* __restrict__ W, const float* __restrict__ bias,
    float* __restrict__ C,
    unsigned short* __restrict__ CHI, unsigned short* __restrict__ CLO, int M)
{
    __shared__ float At[128][32];
    __shared__ float Bs[32][128];
    const int tid = threadIdx.x;
    const int tile0 = blockIdx.x * 32;
    const int r = tid >> 2, part = tid & 3;
    const int gr = tile0 + r;

    if (gr < M) {
        #pragma unroll
        for (int j2 = 0; j2 < 4; j2++) {
            int c = part * 32 + j2 * 8;
            if (PLANEIN) {
                bf16x8 vh = *(const bf16x8*)(AHI + (size_t)gr * 128 + c);
                bf16x8 vl = *(const bf16x8*)(ALO + (size_t)gr * 128 + c);
                #pragma unroll
                for (int q = 0; q < 8; q++)
                    At[c + q][r] = bf2f((unsigned short)vh[q]) + bf2f((unsigned short)vl[q]);
            } else {
                float4 v0 = *(const float4*)(A0 + (size_t)gr * 128 + c);
                float4 v1 = *(const float4*)(A0 + (size_t)gr * 128 + c + 4);
                At[c][r] = v0.x; At[c+1][r] = v0.y; At[c+2][r] = v0.z; At[c+3][r] = v0.w;
                At[c+4][r] = v1.x; At[c+5][r] = v1.y; At[c+6][r] = v1.z; At[c+7][r] = v1.w;
            }
        }
    } else {
        #pragma unroll
        for (int j = 0; j < 8; j++) {
            int c = part * 32 + j * 4;
            At[c][r] = 0.f; At[c+1][r] = 0.f; At[c+2][r] = 0.f; At[c+3][r] = 0.f;
        }
    }

    float acc[4][8];
    #pragma unroll
    for (int i = 0; i < 4; i++)
        #pragma unroll
        for (int j = 0; j < 8; j++) acc[i][j] = 0.f;

    const int tx = tid & 15, ty = tid >> 4;

    for (int kb = 0; kb < 4; kb++) {
        __syncthreads();
        #pragma unroll
        for (int j = 0; j < 8; j++) {
            int li = j * 512 + tid * 4;
            int kk = li >> 7, c = li & 127;
            float4 v = *(const float4*)(W + (size_t)(kb * 32 + kk) * 128 + c);
            *(float4*)&Bs[kk][c] = v;
        }
        __syncthreads();
        #pragma unroll 8
        for (int kk = 0; kk < 32; kk++) {
            float4 a  = *(const float4*)&At[kb * 32 + kk][ty * 4];
            float4 b0 = *(const float4*)&Bs[kk][tx * 8];
            float4 b1 = *(const float4*)&Bs[kk][tx * 8 + 4];
            float av[4] = {a.x, a.y, a.z, a.w};
            float bv[8] = {b0.x, b0.y, b0.z, b0.w, b1.x, b1.y, b1.z, b1.w};
            #pragma unroll
            for (int i = 0; i < 4; i++)
                #pragma unroll
                for (int j = 0; j < 8; j++)
                    acc[i][j] = fmaf(av[i], bv[j], acc[i][j]);
        }
    }

    const int c0 = tx * 8;
    #pragma unroll
    for (int i = 0; i < 4; i++) {
        int grr = tile0 + ty * 4 + i;
        if (grr >= M) continue;
        if (PLANEOUT) {
            float v[8];
            #pragma unroll
            for (int j = 0; j < 8; j++) v[j] = acc[i][j] + bias[c0 + j];
            unsigned int hw[4], lw[4];
            #pragma unroll
            for (int q = 0; q < 4; q++) {
                float a0 = v[2*q], a1 = v[2*q+1];
                unsigned int ua = __float_as_uint(a0) & 0xffff0000u;
                unsigned int ub = __float_as_uint(a1) & 0xffff0000u;
                hw[q] = (ua >> 16) | ub;
                lw[q] = cvtpk2(a0 - __uint_as_float(ua), a1 - __uint_as_float(ub));
            }
            uint4 hv = {hw[0], hw[1], hw[2], hw[3]};
            uint4 lv = {lw[0], lw[1], lw[2], lw[3]};
            *(uint4*)(CHI + (size_t)grr * 128 + c0) = hv;
            *(uint4*)(CLO + (size_t)grr * 128 + c0) = lv;
        } else {
            #pragma unroll
            for (int j = 0; j < 8; j++)
                C[(size_t)grr * 128 + c0 + j] = acc[i][j] + bias[c0 + j];
        }
    }
}

// ---------------- launch ----------------

extern "C" void kernel_launch(void* const* d_in, const int* in_sizes, int n_in,
                              void* d_out, int out_size, void* d_ws, size_t ws_size,
                              hipStream_t stream) {
    const float* H        = (const float*)d_in[0];
    const float* Z        = (const float*)d_in[1];
    const int*   edges    = (const int*)  d_in[4];
    const float* eattr    = (const float*)d_in[5];
    const float* emb_in_w = (const float*)d_in[6];
    const float* emb_in_b = (const float*)d_in[7];
    const float* emb_out_w= (const float*)d_in[8];
    const float* emb_out_b= (const float*)d_in[9];
    const float* edge_w1  = (const float*)d_in[10];
    const float* edge_b1  = (const float*)d_in[11];
    const float* edge_w2  = (const float*)d_in[12];
    const float* edge_b2  = (const float*)d_in[13];
    const float* node_w1  = (const float*)d_in[14];
    const float* node_b1  = (const float*)d_in[15];
    const float* node_w2  = (const float*)d_in[16];
    const float* node_b2  = (const float*)d_in[17];
    const float* coord_w1 = (const float*)d_in[18];
    const float* coord_b1 = (const float*)d_in[19];
    const float* coord_w2 = (const float*)d_in[20];

    float* out  = (float*)d_out;
    float* hbuf = out;                              // [N][128] f32 (final output only)
    float* xout = out + (size_t)NATOM * 128;        // [N][3]

    // workspace (~78 MB), 16B-aligned sections
    char* w = (char*)d_ws;
    unsigned short* hHI = (unsigned short*)w;  w += (size_t)NATOM * 128 * 2;  // 20.48 MB
    unsigned short* hLO = (unsigned short*)w;  w += (size_t)NATOM * 128 * 2;  // 20.48 MB
    unsigned short* msum = (unsigned short*)w; w += (size_t)NGRP * 128 * 2;   // 30.72 MB
    float* xsum = (float*)w;           w += (size_t)NGRP * 3 * 4;             // 1.44 MB
    float* xA  = (float*)w;            w += (size_t)NATOM * 3 * 4;
    float* xB  = (float*)w;            w += (size_t)NATOM * 3 * 4;
    unsigned short* w1f_hi = (unsigned short*)w;  w += (size_t)3 * W1F_L * 2;
    unsigned short* w1f_lo = (unsigned short*)w;  w += (size_t)3 * W1F_L * 2;
    unsigned short* w2f_hi = (unsigned short*)w;  w += (size_t)3 * W2F_L * 2;
    unsigned short* w2f_lo = (unsigned short*)w;  w += (size_t)3 * W2F_L * 2;
    unsigned short* c1f_hi = (unsigned short*)w;  w += (size_t)3 * W2F_L * 2;
    unsigned short* c1f_lo = (unsigned short*)w;  w += (size_t)3 * W2F_L * 2;
    unsigned short* n1f_hi = (unsigned short*)w;  w += (size_t)3 * NW1F_L * 2;
    unsigned short* n1f_lo = (unsigned short*)w;  w += (size_t)3 * NW1F_L * 2;
    unsigned short* n2f_hi = (unsigned short*)w;  w += (size_t)3 * W2F_L * 2;
    unsigned short* n2f_lo = (unsigned short*)w;  w += (size_t)3 * W2F_L * 2;
    int* colIdx = (int*)w;             w += (size_t)EALL * 4;
    int* degB   = (int*)w;             w += (size_t)NBLK * 4;
    int* cursor = (int*)w;             w += (size_t)NBLK * 4;
    int* listE  = (int*)w;             w += (size_t)EBK * 4;
    int* offB   = (int*)w;             w += (size_t)(NBLK + 1) * 4;

    hipMemsetAsync(degB,   0, NBLK * sizeof(int), stream);
    hipMemsetAsync(cursor, 0, NBLK * sizeof(int), stream);

    k_count<<<(EBK + 255) / 256, 256, 0, stream>>>(edges, degB);
    k_scan <<<1, 1024, 0, stream>>>(degB, offB);
    k_fill <<<(EBK + 255) / 256, 256, 0, stream>>>(edges, offB, cursor, listE);
    k_topk <<<(EBK * UU + 255) / 256, 256, 0, stream>>>(edges, Z, colIdx);

    {
        int total = 3 * W1F_L + 3 * W2F_L + 3 * W2F_L + 3 * NW1F_L + 3 * W2F_L;
        k_wfrag<<<(total + 255) / 256, 256, 0, stream>>>(
            edge_w1, edge_w2, coord_w1, node_w1, node_w2,
            w1f_hi, w1f_lo, w2f_hi, w2f_lo, c1f_hi, c1f_lo,
            n1f_hi, n1f_lo, n2f_hi, n2f_lo);
    }

    // h = H @ emb_in_w + b  (write hi/lo planes, vectorized)
    k_gemm<false, true><<<NATOM / 32, 128, 0, stream>>>(
        H, nullptr, nullptr, emb_in_w, emb_in_b, nullptr, hHI, hLO, NATOM);

    const float* xcur = Z;
    for (int l = 0; l < LAY; l++) {
        float* xnext = (l == 0) ? xA : (l == 1) ? xB : xout;

        k_edge_flat<<<EBK / E_WG, 768, 0, stream>>>(
            hHI, hLO, xcur, eattr, edges, colIdx,
            w1f_hi + (size_t)l * W1F_L, w1f_lo + (size_t)l * W1F_L,
            w2f_hi + (size_t)l * W2F_L, w2f_lo + (size_t)l * W2F_L,
            c1f_hi + (size_t)l * W2F_L, c1f_lo + (size_t)l * W2F_L,
            edge_b1 + l * 128, edge_b2 + l * 128, coord_b1 + l * 128, coord_w2 + l * 128,
            msum, xsum);

        k_xupd<<<(NATOM * 3 + 255) / 256, 256, 0, stream>>>(xcur, xsum, offB, listE, xnext);

        k_node<<<(NATOM + NODE_ROWS - 1) / NODE_ROWS, 768, 0, stream>>>(
            hHI, hLO, msum, offB, listE,
            n1f_hi + (size_t)l * NW1F_L, n1f_lo + (size_t)l * NW1F_L,
            n2f_hi + (size_t)l * W2F_L, n2f_lo + (size_t)l * W2F_L,
            node_b1 + l * 128, node_b2 + l * 128);

        xcur = xnext;
    }

    // h_out = h @ emb_out_w + b  (read planes vectorized, write f32 to d_out)
    k_gemm<true, false><<<NATOM / 32, 128, 0, stream>>>(
        nullptr, hHI, hLO, emb_out_w, emb_out_b, hbuf, nullptr, nullptr, NATOM);
}

// Round 14
// 882.033 us; speedup vs baseline: 1.0415x; 1.0114x over previous
//
#include <hip/hip_runtime.h>
#include <math.h>

#define HIDC 128
#define EDGEF 16
#define LAY 3
#define KNN 3
#define UU 4
#define NBLK 20000
#define NATOM (NBLK*UU)      // 80000
#define EBK 30000
#define EALL (EBK*UU*KNN)    // 360000
#define NGRP (EBK*UU)        // 120000 (edge,u) groups

#define W1F_L 36864          // 9 kb * 8 j * 64 lanes * 8
#define W2F_L 16384          // 4 kb * 8 j * 64 lanes * 8
#define NW1F_L 32768         // 8 kb * 8 j * 64 lanes * 8

#define E_WG 16              // block-edges per edge-kernel workgroup
#define ROWS_WG (E_WG*12)    // 192 rows
#define NODE_ROWS 192        // atoms per node-kernel workgroup

typedef __attribute__((ext_vector_type(8))) short bf16x8;
typedef __attribute__((ext_vector_type(4))) float f32x4;

__device__ __forceinline__ float silu_f(float v) {
    return __fdividef(v, 1.0f + __expf(-v));
}

__device__ __forceinline__ unsigned short f2bf(float f) {
    union { float f; unsigned int u; } v; v.f = f;
    unsigned int r = v.u + 0x7FFFu + ((v.u >> 16) & 1u);
    return (unsigned short)(r >> 16);
}

__device__ __forceinline__ float bf2f(unsigned short h) {
    union { unsigned int u; float f; } t; t.u = ((unsigned int)h) << 16;
    return t.f;
}

// full-precision split (RNE hi) — one-time weight prep only
__device__ __forceinline__ void split2(float v, short& hi, short& lo) {
    unsigned short h = f2bf(v);
    hi = (short)h;
    lo = (short)f2bf(v - bf2f(h));
}

// cheap split: truncated hi + RNE lo (lo captures truncation exactly; ~2^-17 rel)
__device__ __forceinline__ void csplit(float v, unsigned short& hi, unsigned short& lo) {
    unsigned int hu = __float_as_uint(v) & 0xffff0000u;
    hi = (unsigned short)(hu >> 16);
    lo = f2bf(v - __uint_as_float(hu));
}

// packed bf16 pair conversion: low16 = bf16(a), high16 = bf16(b)  [T12 recipe]
__device__ __forceinline__ unsigned int cvtpk2(float a, float b) {
    unsigned int r;
    asm("v_cvt_pk_bf16_f32 %0, %1, %2" : "=v"(r) : "v"(a), "v"(b));
    return r;
}

// async global->LDS DMA: 16B per lane, LDS dest = wave-uniform base + lane*16
__device__ __forceinline__ void stage16(const unsigned short* gsrc, unsigned short* ldst) {
    __builtin_amdgcn_global_load_lds(
        (const __attribute__((address_space(1))) unsigned int*)(const void*)gsrc,
        (__attribute__((address_space(3))) unsigned int*)(void*)ldst,
        16, 0, 0);
}

// ---------------- CSR build ----------------

__global__ void k_count(const int* __restrict__ edges, int* __restrict__ degB) {
    int e = blockIdx.x * 256 + threadIdx.x;
    if (e < EBK) atomicAdd(&degB[edges[e]], 1);
}

__global__ void k_scan(const int* __restrict__ degB, int* __restrict__ offB) {
    __shared__ int s[1024];
    __shared__ int carry;
    if (threadIdx.x == 0) carry = 0;
    __syncthreads();
    for (int base = 0; base < NBLK; base += 1024) {
        int i = base + threadIdx.x;
        int v = (i < NBLK) ? degB[i] : 0;
        s[threadIdx.x] = v;
        __syncthreads();
        for (int d = 1; d < 1024; d <<= 1) {
            int t = (threadIdx.x >= d) ? s[threadIdx.x - d] : 0;
            __syncthreads();
            s[threadIdx.x] += t;
            __syncthreads();
        }
        if (i < NBLK) offB[i] = carry + s[threadIdx.x] - v;
        int tot = s[1023];
        __syncthreads();
        if (threadIdx.x == 0) carry += tot;
        __syncthreads();
    }
    if (threadIdx.x == 0) offB[NBLK] = carry;
}

__global__ void k_fill(const int* __restrict__ edges, const int* __restrict__ offB,
                       int* __restrict__ cursor, int* __restrict__ listE) {
    int e = blockIdx.x * 256 + threadIdx.x;
    if (e < EBK) {
        int b = edges[e];
        int p = atomicAdd(&cursor[b], 1);
        listE[offB[b] + p] = e;
    }
}

// top-3 nearest dst atoms per src atom; exact f32, tie -> lower index (matches top_k)
__global__ void k_topk(const int* __restrict__ edges, const float* __restrict__ Z,
                       int* __restrict__ colIdx) {
    int t = blockIdx.x * 256 + threadIdx.x;
    if (t >= EBK * UU) return;
    int e = t >> 2, u = t & 3;
    int b0 = edges[e], b1 = edges[EBK + e];
    int s = b0 * UU + u;
    float zs0 = Z[s*3+0], zs1 = Z[s*3+1], zs2 = Z[s*3+2];
    float d2[UU];
    #pragma unroll
    for (int v = 0; v < UU; v++) {
        int d = b1 * UU + v;
        float a0 = __fsub_rn(zs0, Z[d*3+0]);
        float a1 = __fsub_rn(zs1, Z[d*3+1]);
        float a2 = __fsub_rn(zs2, Z[d*3+2]);
        float p0 = __fmul_rn(a0, a0);
        float p1 = __fmul_rn(a1, a1);
        float p2 = __fmul_rn(a2, a2);
        d2[v] = __fadd_rn(__fadd_rn(p0, p1), p2);
    }
    bool used[UU] = {false, false, false, false};
    #pragma unroll
    for (int k = 0; k < KNN; k++) {
        int best = -1;
        float bd = INFINITY;
        #pragma unroll
        for (int v = 0; v < UU; v++) {
            if (!used[v] && d2[v] < bd) { bd = d2[v]; best = v; }
        }
        used[best] = true;
        colIdx[t * KNN + k] = b1 * UU + best;
    }
}

// ---------------- weight fragment precompute (hi/lo bf16, MFMA B-layout) ----------------

__global__ void k_wfrag(const float* __restrict__ ew1, const float* __restrict__ ew2,
                        const float* __restrict__ cw1,
                        const float* __restrict__ nw1, const float* __restrict__ nw2,
                        unsigned short* __restrict__ w1f_hi, unsigned short* __restrict__ w1f_lo,
                        unsigned short* __restrict__ w2f_hi, unsigned short* __restrict__ w2f_lo,
                        unsigned short* __restrict__ c1f_hi, unsigned short* __restrict__ c1f_lo,
                        unsigned short* __restrict__ n1f_hi, unsigned short* __restrict__ n1f_lo,
                        unsigned short* __restrict__ n2f_hi, unsigned short* __restrict__ n2f_lo) {
    int i = blockIdx.x * 256 + threadIdx.x;
    float v = 0.f;
    unsigned short* dh = nullptr;
    unsigned short* dl = nullptr;
    int di = 0;
    if (i < 3 * W1F_L) {
        int l = i / W1F_L, rem = i % W1F_L;
        int chunk = rem >> 9, lane = (rem >> 3) & 63, t = rem & 7;
        int kb = chunk >> 3, j = chunk & 7;
        int k = kb*32 + (lane >> 4)*8 + t, n = j*16 + (lane & 15);
        v = (k < 273) ? ew1[(size_t)l*273*128 + (size_t)k*128 + n] : 0.f;
        dh = w1f_hi; dl = w1f_lo; di = i;
    } else {
        int i2 = i - 3 * W1F_L;
        if (i2 < 3 * W2F_L) {
            int l = i2 / W2F_L, rem = i2 % W2F_L;
            int chunk = rem >> 9, lane = (rem >> 3) & 63, t = rem & 7;
            int kb = chunk >> 3, j = chunk & 7;
            int k = kb*32 + (lane >> 4)*8 + t, n = j*16 + (lane & 15);
            v = ew2[(size_t)l*128*128 + (size_t)k*128 + n];
            dh = w2f_hi; dl = w2f_lo; di = i2;
        } else {
            int i3 = i2 - 3 * W2F_L;
            if (i3 < 3 * W2F_L) {
                int l = i3 / W2F_L, rem = i3 % W2F_L;
                int chunk = rem >> 9, lane = (rem >> 3) & 63, t = rem & 7;
                int kb = chunk >> 3, j = chunk & 7;
                int k = kb*32 + (lane >> 4)*8 + t, n = j*16 + (lane & 15);
                v = cw1[(size_t)l*128*128 + (size_t)k*128 + n];
                dh = c1f_hi; dl = c1f_lo; di = i3;
            } else {
                int i4 = i3 - 3 * W2F_L;
                if (i4 < 3 * NW1F_L) {
                    int l = i4 / NW1F_L, rem = i4 % NW1F_L;
                    int chunk = rem >> 9, lane = (rem >> 3) & 63, t = rem & 7;
                    int kb = chunk >> 3, j = chunk & 7;
                    int k = kb*32 + (lane >> 4)*8 + t, n = j*16 + (lane & 15);
                    v = nw1[(size_t)l*256*128 + (size_t)k*128 + n];
                    dh = n1f_hi; dl = n1f_lo; di = i4;
                } else {
                    int i5 = i4 - 3 * NW1F_L;
                    if (i5 >= 3 * W2F_L) return;
                    int l = i5 / W2F_L, rem = i5 % W2F_L;
                    int chunk = rem >> 9, lane = (rem >> 3) & 63, t = rem & 7;
                    int kb = chunk >> 3, j = chunk & 7;
                    int k = kb*32 + (lane >> 4)*8 + t, n = j*16 + (lane & 15);
                    v = nw2[(size_t)l*128*128 + (size_t)k*128 + n];
                    dh = n2f_hi; dl = n2f_lo; di = i5;
                }
            }
        }
    }
    short hi, lo;
    split2(v, hi, lo);
    dh[di] = (unsigned short)hi;
    dl[di] = (unsigned short)lo;
}

// ---------------- flat-12 fused edge pipeline (hybrid-precision MFMA) ----------------
// (unchanged — proven at ~211 us)

__global__ __launch_bounds__(768, 6) void k_edge_flat(
    const unsigned short* __restrict__ hHI,
    const unsigned short* __restrict__ hLO,
    const float* __restrict__ x,
    const float* __restrict__ eattr,
    const int* __restrict__ edges0,
    const int* __restrict__ colIdx,
    const unsigned short* __restrict__ w1f_hi, const unsigned short* __restrict__ w1f_lo,
    const unsigned short* __restrict__ w2f_hi, const unsigned short* __restrict__ w2f_lo,
    const unsigned short* __restrict__ c1f_hi, const unsigned short* __restrict__ c1f_lo,
    const float* __restrict__ eb1,
    const float* __restrict__ eb2,
    const float* __restrict__ cb1,
    const float* __restrict__ cw2v,
    unsigned short* __restrict__ msum,
    float* __restrict__ xsum)
{
    __shared__ unsigned short wbufH[4096], wbufL[4096];        // 16 KB
    __shared__ unsigned short Mlds[ROWS_WG * 128];             // 48 KB (C1, then M)
    __shared__ float diffLDS[ROWS_WG][3];                      // 2.25 KB
    __shared__ float pLDS[ROWS_WG];                            // 0.75 KB

    const int tid = threadIdx.x;
    const int wid = tid >> 6, l = tid & 63;
    const int g = l >> 4, er = l & 15;
    const int e_base = blockIdx.x * E_WG;
    const int r0 = wid * 16;

    const int row_g = r0 + er;
    const int e_loc = row_g / 12;
    const int rr = row_g - e_loc * 12;
    const int u = rr / 3;
    const int kk = rr - u * 3;
    const int e = e_base + e_loc;
    const int bs = edges0[e];
    const int srcA = bs * 4 + u;
    const int colA = colIdx[(e * 4 + u) * 3 + kk];
    float rad = 0.f;
    if (g == 0) {
        float dx = x[srcA*3+0] - x[colA*3+0];
        float dy = x[srcA*3+1] - x[colA*3+1];
        float dz = x[srcA*3+2] - x[colA*3+2];
        rad = dx*dx + dy*dy + dz*dz;
        diffLDS[row_g][0] = dx; diffLDS[row_g][1] = dy; diffLDS[row_g][2] = dz;
    }

    const int goff = wid * 512 + l * 8;
    unsigned short* lb0H = wbufH + wid * 512;
    unsigned short* lb1H = wbufH + 2048 + wid * 512;
    unsigned short* lb0L = wbufL + wid * 512;
    unsigned short* lb1L = wbufL + 2048 + wid * 512;

    // ---- phase 1 ----
    {
        f32x4 acc[8];
        #pragma unroll
        for (int jj = 0; jj < 8; jj++) acc[jj] = (f32x4){0.f, 0.f, 0.f, 0.f};

        #pragma unroll 1
        for (int kb = 0; kb < 9; kb++) {
            __syncthreads();
            if (wid < 4) {
                stage16(w1f_hi + (kb << 12) + goff,        lb0H);
                stage16(w1f_hi + (kb << 12) + 2048 + goff, lb1H);
                stage16(w1f_lo + (kb << 12) + goff,        lb0L);
                stage16(w1f_lo + (kb << 12) + 2048 + goff, lb1L);
            }
            bf16x8 ah, al;
            if (kb < 8) {
                const size_t off = (kb < 4) ? ((size_t)srcA * 128 + kb * 32 + g * 8)
                                            : ((size_t)colA * 128 + (kb - 4) * 32 + g * 8);
                ah = *(const bf16x8*)(hHI + off);
                al = *(const bf16x8*)(hLO + off);
            } else {
                float tv[8];
                #pragma unroll
                for (int q = 0; q < 8; q++) tv[q] = 0.f;
                if (g == 0) {
                    tv[0] = rad;
                    #pragma unroll
                    for (int q = 1; q < 8; q++) tv[q] = eattr[(size_t)e*16 + (q-1)];
                } else if (g == 1) {
                    #pragma unroll
                    for (int q = 0; q < 8; q++) tv[q] = eattr[(size_t)e*16 + 7 + q];
                } else if (g == 2) {
                    tv[0] = eattr[(size_t)e*16 + 15];
                }
                #pragma unroll
                for (int q = 0; q < 8; q++) { unsigned short hh, ll; csplit(tv[q], hh, ll); ah[q] = (short)hh; al[q] = (short)ll; }
            }
            __syncthreads();
            __builtin_amdgcn_s_setprio(1);
            #pragma unroll
            for (int jj = 0; jj < 8; jj++) {
                const int off = (jj << 9) + (l << 3);
                bf16x8 wh = *(const bf16x8*)&wbufH[off];
                bf16x8 wl = *(const bf16x8*)&wbufL[off];
                acc[jj] = __builtin_amdgcn_mfma_f32_16x16x32_bf16(ah, wh, acc[jj], 0, 0, 0);
                acc[jj] = __builtin_amdgcn_mfma_f32_16x16x32_bf16(al, wh, acc[jj], 0, 0, 0);
                acc[jj] = __builtin_amdgcn_mfma_f32_16x16x32_bf16(ah, wl, acc[jj], 0, 0, 0);
            }
            __builtin_amdgcn_s_setprio(0);
        }
        #pragma unroll
        for (int jp = 0; jp < 4; jp++) {
            const int n0 = (jp * 2) * 16 + er, n1 = n0 + 16;
            const float b0 = eb1[n0], b1 = eb1[n1];
            #pragma unroll
            for (int reg = 0; reg < 4; reg++) {
                const int row = r0 + g * 4 + reg;
                float v0 = silu_f(acc[jp*2][reg] + b0);
                float v1 = silu_f(acc[jp*2+1][reg] + b1);
                unsigned int pk = cvtpk2(v0, v1);
                const int m = (row & 7) << 3;
                Mlds[row * 128 + (n0 ^ m)] = (unsigned short)pk;
                Mlds[row * 128 + (n1 ^ m)] = (unsigned short)(pk >> 16);
            }
        }
    }

    // ---- phase 2 ----
    {
        f32x4 acc[8];
        #pragma unroll
        for (int jj = 0; jj < 8; jj++) acc[jj] = (f32x4){0.f, 0.f, 0.f, 0.f};

        #pragma unroll 1
        for (int kb = 0; kb < 4; kb++) {
            __syncthreads();
            if (wid < 4) {
                stage16(w2f_hi + (kb << 12) + goff,        lb0H);
                stage16(w2f_hi + (kb << 12) + 2048 + goff, lb1H);
                stage16(w2f_lo + (kb << 12) + goff,        lb0L);
                stage16(w2f_lo + (kb << 12) + 2048 + goff, lb1L);
            }
            const int aoff = row_g * 128 + ((kb * 32 + g * 8) ^ ((row_g & 7) << 3));
            bf16x8 a2 = *(const bf16x8*)&Mlds[aoff];
            __syncthreads();
            __builtin_amdgcn_s_setprio(1);
            #pragma unroll
            for (int jj = 0; jj < 8; jj++) {
                const int off = (jj << 9) + (l << 3);
                bf16x8 wh = *(const bf16x8*)&wbufH[off];
                bf16x8 wl = *(const bf16x8*)&wbufL[off];
                acc[jj] = __builtin_amdgcn_mfma_f32_16x16x32_bf16(a2, wh, acc[jj], 0, 0, 0);
                acc[jj] = __builtin_amdgcn_mfma_f32_16x16x32_bf16(a2, wl, acc[jj], 0, 0, 0);
            }
            __builtin_amdgcn_s_setprio(0);
        }
        #pragma unroll
        for (int jp = 0; jp < 4; jp++) {
            const int n0 = (jp * 2) * 16 + er, n1 = n0 + 16;
            const float b0 = eb2[n0], b1 = eb2[n1];
            #pragma unroll
            for (int reg = 0; reg < 4; reg++) {
                const int row = r0 + g * 4 + reg;
                float v0 = silu_f(acc[jp*2][reg] + b0);
                float v1 = silu_f(acc[jp*2+1][reg] + b1);
                unsigned int pk = cvtpk2(v0, v1);
                const int m = (row & 7) << 3;
                Mlds[row * 128 + (n0 ^ m)] = (unsigned short)pk;
                Mlds[row * 128 + (n1 ^ m)] = (unsigned short)(pk >> 16);
            }
        }
    }

    // ---- phase 3 ----
    {
        f32x4 acc[8];
        #pragma unroll
        for (int jj = 0; jj < 8; jj++) acc[jj] = (f32x4){0.f, 0.f, 0.f, 0.f};

        #pragma unroll 1
        for (int kb = 0; kb < 4; kb++) {
            __syncthreads();
            if (wid < 4) {
                stage16(c1f_hi + (kb << 12) + goff,        lb0H);
                stage16(c1f_hi + (kb << 12) + 2048 + goff, lb1H);
                stage16(c1f_lo + (kb << 12) + goff,        lb0L);
                stage16(c1f_lo + (kb << 12) + 2048 + goff, lb1L);
            }
            const int aoff = row_g * 128 + ((kb * 32 + g * 8) ^ ((row_g & 7) << 3));
            bf16x8 a3 = *(const bf16x8*)&Mlds[aoff];
            __syncthreads();
            __builtin_amdgcn_s_setprio(1);
            #pragma unroll
            for (int jj = 0; jj < 8; jj++) {
                const int off = (jj << 9) + (l << 3);
                bf16x8 wh = *(const bf16x8*)&wbufH[off];
                bf16x8 wl = *(const bf16x8*)&wbufL[off];
                acc[jj] = __builtin_amdgcn_mfma_f32_16x16x32_bf16(a3, wh, acc[jj], 0, 0, 0);
                acc[jj] = __builtin_amdgcn_mfma_f32_16x16x32_bf16(a3, wl, acc[jj], 0, 0, 0);
            }
            __builtin_amdgcn_s_setprio(0);
        }
        float p[4] = {0.f, 0.f, 0.f, 0.f};
        #pragma unroll
        for (int jj = 0; jj < 8; jj++) {
            const int n = jj * 16 + er;
            const float cb = cb1[n], cw = cw2v[n];
            #pragma unroll
            for (int reg = 0; reg < 4; reg++)
                p[reg] += silu_f(acc[jj][reg] + cb) * cw;
        }
        #pragma unroll
        for (int d = 1; d < 16; d <<= 1) {
            #pragma unroll
            for (int reg = 0; reg < 4; reg++)
                p[reg] += __shfl_xor(p[reg], d);
        }
        if (er == 0) {
            #pragma unroll
            for (int reg = 0; reg < 4; reg++)
                pLDS[r0 + g * 4 + reg] = p[reg];
        }
    }
    __syncthreads();

    // ---- merged tail: msum (u32 col-pairs) + xsum ----
    for (int t = tid; t < E_WG * 4 * 64; t += 768) {
        const int gi = t >> 6, cp = t & 63;
        const int c0 = cp * 2;
        const int el = gi >> 2, uu2 = gi & 3;
        const int base = el * 12 + uu2 * 3;
        float s0 = 0.f, s1 = 0.f;
        #pragma unroll
        for (int k3 = 0; k3 < 3; k3++) {
            const int row = base + k3;
            const int m = (row & 7) << 3;
            unsigned int pr = *(const unsigned int*)&Mlds[row * 128 + (c0 ^ m)];
            s0 += bf2f((unsigned short)(pr & 0xffffu));
            s1 += bf2f((unsigned short)(pr >> 16));
        }
        ((unsigned int*)msum)[(size_t)((e_base + el) * 4 + uu2) * 64 + cp] = cvtpk2(s0, s1);
    }
    if (tid < E_WG * 4 * 3) {
        const int gi = tid / 3, c = tid - gi * 3;
        const int el = gi >> 2, uu2 = gi & 3;
        const int base = el * 12 + uu2 * 3;
        float xs = 0.f;
        #pragma unroll
        for (int k3 = 0; k3 < 3; k3++)
            xs += diffLDS[base + k3][c] * pLDS[base + k3];
        xsum[(size_t)((e_base + el) * 4 + uu2) * 3 + c] = xs;
    }
}

// ---------------- fused node MLP + coordinate update ----------------
// WG = 768 threads = 12 waves = 192 atoms. Weight chunks staged once per WG.
// h_new = h + silu([h|agg]@w1+b1)@w2+b2; agg AND xsum gathered via the SAME CSR walk.

__global__ __launch_bounds__(768, 6) void k_node(
    unsigned short* __restrict__ hHI,
    unsigned short* __restrict__ hLO,
    const unsigned short* __restrict__ msum,
    const float* __restrict__ xsum,
    const float* __restrict__ xcur,
    float* __restrict__ xnext,
    const int* __restrict__ offB,
    const int* __restrict__ listE,
    const unsigned short* __restrict__ n1f_hi, const unsigned short* __restrict__ n1f_lo,
    const unsigned short* __restrict__ n2f_hi, const unsigned short* __restrict__ n2f_lo,
    const float* __restrict__ nb1,
    const float* __restrict__ nb2)
{
    __shared__ unsigned short wbufH[4096], wbufL[4096];   // 16 KB
    __shared__ unsigned short hid[NODE_ROWS * 128];       // 48 KB

    const int tid = threadIdx.x;
    const int wid = tid >> 6, l = tid & 63;
    const int g = l >> 4, er = l & 15;
    const int r0 = wid * 16;
    const int row_g = r0 + er;
    const int a = blockIdx.x * NODE_ROWS + row_g;
    const bool aOK = (a < NATOM);
    const int aC = aOK ? a : 0;
    const int b = aC >> 2, u = aC & 3;
    const int o0 = aOK ? offB[b] : 0;
    const int o1 = aOK ? offB[b + 1] : 0;

    const int goff = wid * 512 + l * 8;    // valid for wid<4 staging
    unsigned short* lb0H = wbufH + wid * 512;
    unsigned short* lb1H = wbufH + 2048 + wid * 512;
    unsigned short* lb0L = wbufL + wid * 512;
    unsigned short* lb1L = wbufL + 2048 + wid * 512;

    float xs0 = 0.f, xs1 = 0.f, xs2 = 0.f;

    // ---- phase A: hid = silu([h|agg] @ W1 + b1), K=256, 3-MFMA split ----
    {
        f32x4 acc[8];
        #pragma unroll
        for (int jj = 0; jj < 8; jj++) acc[jj] = (f32x4){0.f, 0.f, 0.f, 0.f};

        #pragma unroll 1
        for (int kb = 0; kb < 8; kb++) {
            __syncthreads();
            if (wid < 4) {
                stage16(n1f_hi + (kb << 12) + goff,        lb0H);
                stage16(n1f_hi + (kb << 12) + 2048 + goff, lb1H);
                stage16(n1f_lo + (kb << 12) + goff,        lb0L);
                stage16(n1f_lo + (kb << 12) + 2048 + goff, lb1L);
            }
            bf16x8 ah, al;
            if (kb < 4) {
                const size_t off = (size_t)aC * 128 + kb * 32 + g * 8;
                ah = *(const bf16x8*)(hHI + off);
                al = *(const bf16x8*)(hLO + off);
            } else {
                float s[8];
                #pragma unroll
                for (int q = 0; q < 8; q++) s[q] = 0.f;
                const bool doX = (kb == 4) && (g == 0);
                for (int pos = o0; pos < o1; pos++) {
                    const int e = listE[pos];
                    bf16x8 mv = *(const bf16x8*)(msum + (size_t)(e * 4 + u) * 128 + (kb - 4) * 32 + g * 8);
                    #pragma unroll
                    for (int q = 0; q < 8; q++) s[q] += bf2f((unsigned short)mv[q]);
                    if (doX) {
                        const float* xp = xsum + (size_t)(e * 4 + u) * 3;
                        xs0 += xp[0]; xs1 += xp[1]; xs2 += xp[2];
                    }
                }
                #pragma unroll
                for (int q = 0; q < 8; q++) { unsigned short hh, ll; csplit(s[q], hh, ll); ah[q] = (short)hh; al[q] = (short)ll; }
            }
            __syncthreads();
            __builtin_amdgcn_s_setprio(1);
            #pragma unroll
            for (int jj = 0; jj < 8; jj++) {
                const int off = (jj << 9) + (l << 3);
                bf16x8 wh = *(const bf16x8*)&wbufH[off];
                bf16x8 wl = *(const bf16x8*)&wbufL[off];
                acc[jj] = __builtin_amdgcn_mfma_f32_16x16x32_bf16(ah, wh, acc[jj], 0, 0, 0);
                acc[jj] = __builtin_amdgcn_mfma_f32_16x16x32_bf16(al, wh, acc[jj], 0, 0, 0);
                acc[jj] = __builtin_amdgcn_mfma_f32_16x16x32_bf16(ah, wl, acc[jj], 0, 0, 0);
            }
            __builtin_amdgcn_s_setprio(0);
        }
        // coordinate update (one lane per atom; same CSR sum as the old k_xupd)
        if (aOK && g == 0) {
            const int deg = o1 - o0;
            const float inv = (deg > 0) ? __fdividef(1.0f, 3.0f * (float)deg) : 0.f;
            xnext[aC*3+0] = xcur[aC*3+0] + xs0 * inv;
            xnext[aC*3+1] = xcur[aC*3+1] + xs1 * inv;
            xnext[aC*3+2] = xcur[aC*3+2] + xs2 * inv;
        }
        #pragma unroll
        for (int jp = 0; jp < 4; jp++) {
            const int n0 = (jp * 2) * 16 + er, n1 = n0 + 16;
            const float b0 = nb1[n0], b1 = nb1[n1];
            #pragma unroll
            for (int reg = 0; reg < 4; reg++) {
                const int row = r0 + g * 4 + reg;
                float v0 = silu_f(acc[jp*2][reg] + b0);
                float v1 = silu_f(acc[jp*2+1][reg] + b1);
                unsigned int pk = cvtpk2(v0, v1);
                const int m = (row & 7) << 3;
                hid[row * 128 + (n0 ^ m)] = (unsigned short)pk;
                hid[row * 128 + (n1 ^ m)] = (unsigned short)(pk >> 16);
            }
        }
    }

    // ---- phase B: h += hid @ W2 + b2, K=128, 2-MFMA ----
    {
        f32x4 acc[8];
        #pragma unroll
        for (int jj = 0; jj < 8; jj++) acc[jj] = (f32x4){0.f, 0.f, 0.f, 0.f};

        #pragma unroll 1
        for (int kb = 0; kb < 4; kb++) {
            __syncthreads();
            if (wid < 4) {
                stage16(n2f_hi + (kb << 12) + goff,        lb0H);
                stage16(n2f_hi + (kb << 12) + 2048 + goff, lb1H);
                stage16(n2f_lo + (kb << 12) + goff,        lb0L);
                stage16(n2f_lo + (kb << 12) + 2048 + goff, lb1L);
            }
            const int aoff = row_g * 128 + ((kb * 32 + g * 8) ^ ((row_g & 7) << 3));
            bf16x8 ab = *(const bf16x8*)&hid[aoff];
            __syncthreads();
            __builtin_amdgcn_s_setprio(1);
            #pragma unroll
            for (int jj = 0; jj < 8; jj++) {
                const int off = (jj << 9) + (l << 3);
                bf16x8 wh = *(const bf16x8*)&wbufH[off];
                bf16x8 wl = *(const bf16x8*)&wbufL[off];
                acc[jj] = __builtin_amdgcn_mfma_f32_16x16x32_bf16(ab, wh, acc[jj], 0, 0, 0);
                acc[jj] = __builtin_amdgcn_mfma_f32_16x16x32_bf16(ab, wl, acc[jj], 0, 0, 0);
            }
            __builtin_amdgcn_s_setprio(0);
        }
        #pragma unroll
        for (int jj = 0; jj < 8; jj++) {
            const int n = jj * 16 + er;
            const float bv = nb2[n];
            #pragma unroll
            for (int reg = 0; reg < 4; reg++) {
                const int row = r0 + g * 4 + reg;
                const int aw = blockIdx.x * NODE_ROWS + row;
                if (aw < NATOM) {
                    const size_t idx = (size_t)aw * 128 + n;
                    float v = acc[jj][reg] + bv + bf2f(hHI[idx]) + bf2f(hLO[idx]);
                    unsigned short hh, ll; csplit(v, hh, ll);
                    hHI[idx] = hh;
                    hLO[idx] = ll;
                }
            }
        }
    }
}

// ---------------- generic tiled f32 GEMM (emb MLPs; vectorized plane I/O) ----------------

template<bool PLANEIN, bool PLANEOUT>
__global__ __launch_bounds__(128) void k_gemm(
    const float* __restrict__ A0,
    const unsigned short* __restrict__ AHI, const unsigned short* __restrict__ ALO,
    const float* __restrict__ W, const float* __restrict__ bias,
    float* __restrict__ C,
    unsigned short* __restrict__ CHI, unsigned short* __restrict__ CLO, int M)
{
    __shared__ float At[128][32];
    __shared__ float Bs[32][128];
    const int tid = threadIdx.x;
    const int tile0 = blockIdx.x * 32;
    const int r = tid >> 2, part = tid & 3;
    const int gr = tile0 + r;

    if (gr < M) {
        #pragma unroll
        for (int j2 = 0; j2 < 4; j2++) {
            int c = part * 32 + j2 * 8;
            if (PLANEIN) {
                bf16x8 vh = *(const bf16x8*)(AHI + (size_t)gr * 128 + c);
                bf16x8 vl = *(const bf16x8*)(ALO + (size_t)gr * 128 + c);
                #pragma unroll
                for (int q = 0; q < 8; q++)
                    At[c + q][r] = bf2f((unsigned short)vh[q]) + bf2f((unsigned short)vl[q]);
            } else {
                float4 v0 = *(const float4*)(A0 + (size_t)gr * 128 + c);
                float4 v1 = *(const float4*)(A0 + (size_t)gr * 128 + c + 4);
                At[c][r] = v0.x; At[c+1][r] = v0.y; At[c+2][r] = v0.z; At[c+3][r] = v0.w;
                At[c+4][r] = v1.x; At[c+5][r] = v1.y; At[c+6][r] = v1.z; At[c+7][r] = v1.w;
            }
        }
    } else {
        #pragma unroll
        for (int j = 0; j < 8; j++) {
            int c = part * 32 + j * 4;
            At[c][r] = 0.f; At[c+1][r] = 0.f; At[c+2][r] = 0.f; At[c+3][r] = 0.f;
        }
    }

    float acc[4][8];
    #pragma unroll
    for (int i = 0; i < 4; i++)
        #pragma unroll
        for (int j = 0; j < 8; j++) acc[i][j] = 0.f;

    const int tx = tid & 15, ty = tid >> 4;

    for (int kb = 0; kb < 4; kb++) {
        __syncthreads();
        #pragma unroll
        for (int j = 0; j < 8; j++) {
            int li = j * 512 + tid * 4;
            int kk = li >> 7, c = li & 127;
            float4 v = *(const float4*)(W + (size_t)(kb * 32 + kk) * 128 + c);
            *(float4*)&Bs[kk][c] = v;
        }
        __syncthreads();
        #pragma unroll 8
        for (int kk = 0; kk < 32; kk++) {
            float4 a  = *(const float4*)&At[kb * 32 + kk][ty * 4];
            float4 b0 = *(const float4*)&Bs[kk][tx * 8];
            float4 b1 = *(const float4*)&Bs[kk][tx * 8 + 4];
            float av[4] = {a.x, a.y, a.z, a.w};
            float bv[8] = {b0.x, b0.y, b0.z, b0.w, b1.x, b1.y, b1.z, b1.w};
            #pragma unroll
            for (int i = 0; i < 4; i++)
                #pragma unroll
                for (int j = 0; j < 8; j++)
                    acc[i][j] = fmaf(av[i], bv[j], acc[i][j]);
        }
    }

    const int c0 = tx * 8;
    #pragma unroll
    for (int i = 0; i < 4; i++) {
        int grr = tile0 + ty * 4 + i;
        if (grr >= M) continue;
        if (PLANEOUT) {
            float v[8];
            #pragma unroll
            for (int j = 0; j < 8; j++) v[j] = acc[i][j] + bias[c0 + j];
            unsigned int hw[4], lw[4];
            #pragma unroll
            for (int q = 0; q < 4; q++) {
                float a0 = v[2*q], a1 = v[2*q+1];
                unsigned int ua = __float_as_uint(a0) & 0xffff0000u;
                unsigned int ub = __float_as_uint(a1) & 0xffff0000u;
                hw[q] = (ua >> 16) | ub;
                lw[q] = cvtpk2(a0 - __uint_as_float(ua), a1 - __uint_as_float(ub));
            }
            uint4 hv = {hw[0], hw[1], hw[2], hw[3]};
            uint4 lv = {lw[0], lw[1], lw[2], lw[3]};
            *(uint4*)(CHI + (size_t)grr * 128 + c0) = hv;
            *(uint4*)(CLO + (size_t)grr * 128 + c0) = lv;
        } else {
            #pragma unroll
            for (int j = 0; j < 8; j++)
                C[(size_t)grr * 128 + c0 + j] = acc[i][j] + bias[c0 + j];
        }
    }
}

// ---------------- launch ----------------

extern "C" void kernel_launch(void* const* d_in, const int* in_sizes, int n_in,
                              void* d_out, int out_size, void* d_ws, size_t ws_size,
                              hipStream_t stream) {
    const float* H        = (const float*)d_in[0];
    const float* Z        = (const float*)d_in[1];
    const int*   edges    = (const int*)  d_in[4];
    const float* eattr    = (const float*)d_in[5];
    const float* emb_in_w = (const float*)d_in[6];
    const float* emb_in_b = (const float*)d_in[7];
    const float* emb_out_w= (const float*)d_in[8];
    const float* emb_out_b= (const float*)d_in[9];
    const float* edge_w1  = (const float*)d_in[10];
    const float* edge_b1  = (const float*)d_in[11];
    const float* edge_w2  = (const float*)d_in[12];
    const float* edge_b2  = (const float*)d_in[13];
    const float* node_w1  = (const float*)d_in[14];
    const float* node_b1  = (const float*)d_in[15];
    const float* node_w2  = (const float*)d_in[16];
    const float* node_b2  = (const float*)d_in[17];
    const float* coord_w1 = (const float*)d_in[18];
    const float* coord_b1 = (const float*)d_in[19];
    const float* coord_w2 = (const float*)d_in[20];

    float* out  = (float*)d_out;
    float* hbuf = out;                              // [N][128] f32 (final output only)
    float* xout = out + (size_t)NATOM * 128;        // [N][3]

    // workspace (~78 MB), 16B-aligned sections
    char* w = (char*)d_ws;
    unsigned short* hHI = (unsigned short*)w;  w += (size_t)NATOM * 128 * 2;  // 20.48 MB
    unsigned short* hLO = (unsigned short*)w;  w += (size_t)NATOM * 128 * 2;  // 20.48 MB
    unsigned short* msum = (unsigned short*)w; w += (size_t)NGRP * 128 * 2;   // 30.72 MB
    float* xsum = (float*)w;           w += (size_t)NGRP * 3 * 4;             // 1.44 MB
    float* xA  = (float*)w;            w += (size_t)NATOM * 3 * 4;
    float* xB  = (float*)w;            w += (size_t)NATOM * 3 * 4;
    unsigned short* w1f_hi = (unsigned short*)w;  w += (size_t)3 * W1F_L * 2;
    unsigned short* w1f_lo = (unsigned short*)w;  w += (size_t)3 * W1F_L * 2;
    unsigned short* w2f_hi = (unsigned short*)w;  w += (size_t)3 * W2F_L * 2;
    unsigned short* w2f_lo = (unsigned short*)w;  w += (size_t)3 * W2F_L * 2;
    unsigned short* c1f_hi = (unsigned short*)w;  w += (size_t)3 * W2F_L * 2;
    unsigned short* c1f_lo = (unsigned short*)w;  w += (size_t)3 * W2F_L * 2;
    unsigned short* n1f_hi = (unsigned short*)w;  w += (size_t)3 * NW1F_L * 2;
    unsigned short* n1f_lo = (unsigned short*)w;  w += (size_t)3 * NW1F_L * 2;
    unsigned short* n2f_hi = (unsigned short*)w;  w += (size_t)3 * W2F_L * 2;
    unsigned short* n2f_lo = (unsigned short*)w;  w += (size_t)3 * W2F_L * 2;
    int* colIdx = (int*)w;             w += (size_t)EALL * 4;
    int* degB   = (int*)w;             w += (size_t)NBLK * 4;
    int* cursor = (int*)w;             w += (size_t)NBLK * 4;
    int* listE  = (int*)w;             w += (size_t)EBK * 4;
    int* offB   = (int*)w;             w += (size_t)(NBLK + 1) * 4;

    hipMemsetAsync(degB,   0, NBLK * sizeof(int), stream);
    hipMemsetAsync(cursor, 0, NBLK * sizeof(int), stream);

    k_count<<<(EBK + 255) / 256, 256, 0, stream>>>(edges, degB);
    k_scan <<<1, 1024, 0, stream>>>(degB, offB);
    k_fill <<<(EBK + 255) / 256, 256, 0, stream>>>(edges, offB, cursor, listE);
    k_topk <<<(EBK * UU + 255) / 256, 256, 0, stream>>>(edges, Z, colIdx);

    {
        int total = 3 * W1F_L + 3 * W2F_L + 3 * W2F_L + 3 * NW1F_L + 3 * W2F_L;
        k_wfrag<<<(total + 255) / 256, 256, 0, stream>>>(
            edge_w1, edge_w2, coord_w1, node_w1, node_w2,
            w1f_hi, w1f_lo, w2f_hi, w2f_lo, c1f_hi, c1f_lo,
            n1f_hi, n1f_lo, n2f_hi, n2f_lo);
    }

    // h = H @ emb_in_w + b  (write hi/lo planes, vectorized)
    k_gemm<false, true><<<NATOM / 32, 128, 0, stream>>>(
        H, nullptr, nullptr, emb_in_w, emb_in_b, nullptr, hHI, hLO, NATOM);

    const float* xcur = Z;
    for (int l = 0; l < LAY; l++) {
        float* xnext = (l == 0) ? xA : (l == 1) ? xB : xout;

        k_edge_flat<<<EBK / E_WG, 768, 0, stream>>>(
            hHI, hLO, xcur, eattr, edges, colIdx,
            w1f_hi + (size_t)l * W1F_L, w1f_lo + (size_t)l * W1F_L,
            w2f_hi + (size_t)l * W2F_L, w2f_lo + (size_t)l * W2F_L,
            c1f_hi + (size_t)l * W2F_L, c1f_lo + (size_t)l * W2F_L,
            edge_b1 + l * 128, edge_b2 + l * 128, coord_b1 + l * 128, coord_w2 + l * 128,
            msum, xsum);

        k_node<<<(NATOM + NODE_ROWS - 1) / NODE_ROWS, 768, 0, stream>>>(
            hHI, hLO, msum, xsum, xcur, xnext, offB, listE,
            n1f_hi + (size_t)l * NW1F_L, n1f_lo + (size_t)l * NW1F_L,
            n2f_hi + (size_t)l * W2F_L, n2f_lo + (size_t)l * W2F_L,
            node_b1 + l * 128, node_b2 + l * 128);

        xcur = xnext;
    }

    // h_out = h @ emb_out_w + b  (read planes vectorized, write f32 to d_out)
    k_gemm<true, false><<<NATOM / 32, 128, 0, stream>>>(
        nullptr, hHI, hLO, emb_out_w, emb_out_b, hbuf, nullptr, nullptr, NATOM);
}